// Round 1
// baseline (1745.867 us; speedup 1.0000x reference)
//
#include <hip/hip_runtime.h>

#define B_ 8
#define C_ 256
#define HW_ 2304
#define E_ 64
#define SB_ (C_*HW_)  // 589824 floats per batch

// workspace layout (float offsets)
#define WS_GAP   0          // 2048
#define WS_ATTC  2048       // 524288
#define WS_Q     526336     // 1179648
#define WS_K     1705984    // 1179648
#define WS_V     2885632    // 1179648
#define WS_M     4065280    // 18432
#define WS_RL    4083712    // 18432
#define WS_GS    4102144    // 1179648
// total = 5281792 floats = 21.1 MB

// ---- GAP: mean over HW per (b,c) ----
__global__ __launch_bounds__(256) void k_gap(const float* __restrict__ f, float* __restrict__ gap){
  int bc = blockIdx.x;
  const float* row = f + (size_t)bc * HW_;
  float s = 0.f;
  for (int i = threadIdx.x; i < HW_; i += 256) s += row[i];
  #pragma unroll
  for (int off = 32; off; off >>= 1) s += __shfl_down(s, off);
  __shared__ float red[4];
  int lane = threadIdx.x & 63, wv = threadIdx.x >> 6;
  if (lane == 0) red[wv] = s;
  __syncthreads();
  if (threadIdx.x == 0) gap[bc] = (red[0]+red[1]+red[2]+red[3]) * (1.0f/HW_);
}

// ---- conv1d(k=3)+sigmoid for query/key, rank-1 scores, softmax over i ----
__global__ __launch_bounds__(256) void k_attc(const float* __restrict__ gap,
    const float* __restrict__ wq1, const float* __restrict__ bq1,
    const float* __restrict__ wk1, const float* __restrict__ bk1,
    float* __restrict__ attc){
  int b = blockIdx.x >> 8;
  int j = blockIdx.x & 255;
  int i = threadIdx.x;
  const float* g = gap + b*C_;
  float gm1 = (i > 0)      ? g[i-1] : 0.f;
  float g0  = g[i];
  float gp1 = (i < C_-1)   ? g[i+1] : 0.f;
  float keyv = wk1[0]*gm1 + wk1[1]*g0 + wk1[2]*gp1 + bk1[0];
  keyv = 1.f/(1.f+__expf(-keyv));
  float qm1 = (j > 0)      ? g[j-1] : 0.f;
  float q0  = g[j];
  float qp1 = (j < C_-1)   ? g[j+1] : 0.f;
  float qv = wq1[0]*qm1 + wq1[1]*q0 + wq1[2]*qp1 + bq1[0];
  qv = 1.f/(1.f+__expf(-qv));
  float s = keyv * qv;
  __shared__ float red[256];
  red[i] = s; __syncthreads();
  for (int st = 128; st > 0; st >>= 1){ if (i < st) red[i] = fmaxf(red[i], red[i+st]); __syncthreads(); }
  float mx = red[0]; __syncthreads();
  float e = __expf(s - mx);
  red[i] = e; __syncthreads();
  for (int st = 128; st > 0; st >>= 1){ if (i < st) red[i] += red[i+st]; __syncthreads(); }
  float sum = red[0];
  attc[(size_t)b*C_*C_ + (size_t)i*C_ + j] = e / sum;
}

// ---- q/k/v projections: (64x256)@(256x2304) per batch, z selects matrix ----
__global__ __launch_bounds__(256) void k_proj(const float* __restrict__ f,
    const float* __restrict__ wq, const float* __restrict__ bq,
    const float* __restrict__ wk, const float* __restrict__ bk,
    const float* __restrict__ wv, const float* __restrict__ bv,
    float* __restrict__ q, float* __restrict__ k, float* __restrict__ v){
  int b = blockIdx.x, sc = blockIdx.y, mz = blockIdx.z;
  const float* w  = (mz==0) ? wq : ((mz==1) ? wk : wv);
  const float* bi = (mz==0) ? bq : ((mz==1) ? bk : bv);
  float* o        = (mz==0) ? q  : ((mz==1) ? k  : v);
  __shared__ float lw[E_*C_];   // 64KB
  for (int n = threadIdx.x; n < E_*C_; n += 256) lw[n] = w[n];
  __syncthreads();
  int s = sc*256 + threadIdx.x;
  const float* fb = f + (size_t)b*SB_ + s;
  float acc[E_];
  #pragma unroll
  for (int e = 0; e < E_; e++) acc[e] = 0.f;
  for (int c = 0; c < C_; c++){
    float fv = fb[(size_t)c*HW_];
    #pragma unroll
    for (int e = 0; e < E_; e++) acc[e] += lw[e*C_ + c] * fv;
  }
  float* ob = o + (size_t)b*E_*HW_ + s;
  #pragma unroll
  for (int e = 0; e < E_; e++) ob[(size_t)e*HW_] = acc[e] + bi[e];
}

// ---- pass 1: per-row (i) online max / sum-exp over all j ----
__global__ __launch_bounds__(256) void k_stats(const float* __restrict__ q,
    const float* __restrict__ kk, float* __restrict__ mout, float* __restrict__ rlout){
  int b = blockIdx.x; int i0 = blockIdx.y * 32;
  __shared__ float kl[2048];           // [e][ii] 64x32
  const float* kb = kk + (size_t)b*E_*HW_;
  for (int n = threadIdx.x; n < 2048; n += 256){
    int e = n >> 5, ii = n & 31;
    kl[n] = kb[(size_t)e*HW_ + i0 + ii];
  }
  __syncthreads();
  const float* qb = q + (size_t)b*E_*HW_;
  float m[32], l[32];
  #pragma unroll
  for (int x = 0; x < 32; x++){ m[x] = -1e30f; l[x] = 0.f; }
  for (int jc = 0; jc < 9; jc++){
    int j = jc*256 + threadIdx.x;
    float part[32];
    #pragma unroll
    for (int x = 0; x < 32; x++) part[x] = 0.f;
    for (int e = 0; e < E_; e++){
      float qv = qb[(size_t)e*HW_ + j];
      #pragma unroll
      for (int x = 0; x < 32; x++) part[x] += kl[e*32 + x] * qv;
    }
    #pragma unroll
    for (int x = 0; x < 32; x++){
      float s = part[x];
      float mn = fmaxf(m[x], s);
      l[x] = l[x]*__expf(m[x]-mn) + __expf(s-mn);
      m[x] = mn;
    }
  }
  // merge across 64 lanes
  #pragma unroll
  for (int x = 0; x < 32; x++){
    for (int off = 1; off < 64; off <<= 1){
      float om = __shfl_xor(m[x], off);
      float ol = __shfl_xor(l[x], off);
      float mn = fmaxf(m[x], om);
      l[x] = l[x]*__expf(m[x]-mn) + ol*__expf(om-mn);
      m[x] = mn;
    }
  }
  __shared__ float rm[4][32], rls[4][32];
  int lane = threadIdx.x & 63, wv = threadIdx.x >> 6;
  if (lane == 0){
    #pragma unroll
    for (int x = 0; x < 32; x++){ rm[wv][x] = m[x]; rls[wv][x] = l[x]; }
  }
  __syncthreads();
  if (threadIdx.x < 32){
    int x = threadIdx.x;
    float mm = rm[0][x], ll = rls[0][x];
    #pragma unroll
    for (int w = 1; w < 4; w++){
      float om = rm[w][x], ol = rls[w][x];
      float mn = fmaxf(mm, om);
      ll = ll*__expf(mm-mn) + ol*__expf(om-mn);
      mm = mn;
    }
    mout[b*HW_ + i0 + x] = mm;
    rlout[b*HW_ + i0 + x] = 1.0f / ll;
  }
}

// ---- pass 2: gs[e,j] = sum_i v[e,i] * exp(k_i . q_j - m_i) / l_i ----
__global__ __launch_bounds__(256) void k_gs(const float* __restrict__ q,
    const float* __restrict__ kk, const float* __restrict__ vv,
    const float* __restrict__ mbuf, const float* __restrict__ rlbuf,
    float* __restrict__ gs){
  int b = blockIdx.x; int j0 = blockIdx.y * 64;
  int t = threadIdx.x; int jl = t & 63; int seg = t >> 6;
  int j = j0 + jl;
  __shared__ float smem[16384];        // 64KB: staging then reduce
  const float* qb = q  + (size_t)b*E_*HW_;
  const float* kb = kk + (size_t)b*E_*HW_;
  const float* vb = vv + (size_t)b*E_*HW_;
  const float* mb = mbuf  + b*HW_;
  const float* rb = rlbuf + b*HW_;
  float qreg[E_];
  #pragma unroll
  for (int e = 0; e < E_; e++) qreg[e] = qb[(size_t)e*HW_ + j];
  float acc[E_];
  #pragma unroll
  for (int e = 0; e < E_; e++) acc[e] = 0.f;
  for (int ic = 0; ic < 18; ic++){
    __syncthreads();
    for (int n = t; n < 8192; n += 256){
      int seg2 = n >> 11, e = (n >> 5) & 63, ii = n & 31;
      int gi = seg2*576 + ic*32 + ii;
      smem[n]        = kb[(size_t)e*HW_ + gi];
      smem[8192 + n] = vb[(size_t)e*HW_ + gi];
    }
    __syncthreads();
    const float* klp = smem + seg*2048;
    const float* vlp = smem + 8192 + seg*2048;
    #pragma unroll 1
    for (int ii = 0; ii < 32; ii++){
      int i = seg*576 + ic*32 + ii;
      float s = 0.f;
      #pragma unroll
      for (int e = 0; e < E_; e++) s += qreg[e] * klp[e*32 + ii];
      float w = __expf(s - mb[i]) * rb[i];
      #pragma unroll
      for (int e = 0; e < E_; e++) acc[e] += w * vlp[e*32 + ii];
    }
  }
  __syncthreads();
  #pragma unroll
  for (int e = 0; e < E_; e++) smem[seg*4096 + e*64 + jl] = acc[e];
  __syncthreads();
  float* gb = gs + (size_t)b*E_*HW_;
  for (int o = t; o < 4096; o += 256){
    float s4 = smem[o] + smem[4096+o] + smem[8192+o] + smem[12288+o];
    int e = o >> 6, jj = o & 63;
    gb[(size_t)e*HW_ + j0 + jj] = s4;
  }
}

// ---- gsout[c,s] = sum_e watt[c,e]*gs[e,s] + batt[c]  (staged in d_out) ----
__global__ __launch_bounds__(256) void k_gsout(const float* __restrict__ gs,
    const float* __restrict__ watt, const float* __restrict__ batt,
    float* __restrict__ gsout){
  int b = blockIdx.x; int sc = blockIdx.y; int cc0 = blockIdx.z * 16;
  int s = sc*256 + threadIdx.x;
  __shared__ float lw[1024];
  for (int n = threadIdx.x; n < 1024; n += 256) lw[n] = watt[cc0*E_ + n];
  __syncthreads();
  const float* gb = gs + (size_t)b*E_*HW_ + s;
  float acc[16];
  #pragma unroll
  for (int x = 0; x < 16; x++) acc[x] = 0.f;
  for (int e = 0; e < E_; e++){
    float gv = gb[(size_t)e*HW_];
    #pragma unroll
    for (int x = 0; x < 16; x++) acc[x] += lw[x*64 + e] * gv;
  }
  float* ob = gsout + (size_t)b*SB_ + (size_t)cc0*HW_ + s;
  #pragma unroll
  for (int x = 0; x < 16; x++) ob[(size_t)x*HW_] = acc[x] + batt[cc0 + x];
}

// ---- final: gc GEMM (V @ att_c) fused with out = f*gc*(gsout+1), in-place on d_out ----
__global__ __launch_bounds__(256) void k_final(const float* __restrict__ f,
    const float* __restrict__ attc, const float* __restrict__ gsout,
    float* __restrict__ out){
  int b = blockIdx.x; int p0 = blockIdx.y * 64;
  int j = threadIdx.x;
  __shared__ float A[16384];           // 64 rows of V (contiguous 64KB of feature)
  const float* fb = f + (size_t)b*SB_ + (size_t)p0*C_;
  for (int n = j; n < 16384; n += 256) A[n] = fb[n];
  __syncthreads();
  const float* ab = attc + (size_t)b*C_*C_;
  float acc[64];
  #pragma unroll
  for (int p = 0; p < 64; p++) acc[p] = 0.f;
  for (int i = 0; i < C_; i++){
    float bv = ab[(size_t)i*C_ + j];
    #pragma unroll
    for (int p = 0; p < 64; p++) acc[p] += A[p*256 + i] * bv;
  }
  const float* gb = gsout + (size_t)b*SB_ + (size_t)p0*C_;
  float* ob = out + (size_t)b*SB_ + (size_t)p0*C_;
  #pragma unroll
  for (int p = 0; p < 64; p++){
    float fx = A[p*256 + j];
    float g  = gb[p*256 + j];
    ob[p*256 + j] = acc[p] * fx * (g + 1.f);
  }
}

extern "C" void kernel_launch(void* const* d_in, const int* in_sizes, int n_in,
                              void* d_out, int out_size, void* d_ws, size_t ws_size,
                              hipStream_t stream){
  const float* f    = (const float*)d_in[0];
  const float* wq1  = (const float*)d_in[1];
  const float* bq1  = (const float*)d_in[2];
  const float* wk1  = (const float*)d_in[3];
  const float* bk1  = (const float*)d_in[4];
  const float* wq2  = (const float*)d_in[5];
  const float* bq2  = (const float*)d_in[6];
  const float* wk2  = (const float*)d_in[7];
  const float* bk2  = (const float*)d_in[8];
  const float* wv2  = (const float*)d_in[9];
  const float* bv2  = (const float*)d_in[10];
  const float* watt = (const float*)d_in[11];
  const float* batt = (const float*)d_in[12];
  float* out = (float*)d_out;
  float* ws  = (float*)d_ws;

  float* gap  = ws + WS_GAP;
  float* attc = ws + WS_ATTC;
  float* q    = ws + WS_Q;
  float* k    = ws + WS_K;
  float* v    = ws + WS_V;
  float* m    = ws + WS_M;
  float* rl   = ws + WS_RL;
  float* gs   = ws + WS_GS;

  k_gap  <<<B_*C_,            256, 0, stream>>>(f, gap);
  k_attc <<<B_*C_,            256, 0, stream>>>(gap, wq1, bq1, wk1, bk1, attc);
  k_proj <<<dim3(B_, 9, 3),   256, 0, stream>>>(f, wq2, bq2, wk2, bk2, wv2, bv2, q, k, v);
  k_stats<<<dim3(B_, 72),     256, 0, stream>>>(q, k, m, rl);
  k_gs   <<<dim3(B_, 36),     256, 0, stream>>>(q, k, v, m, rl, gs);
  k_gsout<<<dim3(B_, 9, 16),  256, 0, stream>>>(gs, watt, batt, out);
  k_final<<<dim3(B_, 36),     256, 0, stream>>>(f, attc, out, out);
}

// Round 2
// 734.520 us; speedup vs baseline: 2.3769x; 2.3769x over previous
//
#include <hip/hip_runtime.h>

#define B_ 8
#define C_ 256
#define HW_ 2304
#define E_ 64
#define SB_ (C_*HW_)  // 589824 floats per batch

typedef unsigned short u16;
typedef __attribute__((ext_vector_type(8))) __bf16 bf16x8;
typedef __attribute__((ext_vector_type(4))) float f32x4;
#define MFMA16(a,b,c) __builtin_amdgcn_mfma_f32_16x16x32_bf16(a,b,c,0,0,0)

// fp32 -> bf16 RNE via integer ops (no __bf16 scalar arithmetic needed)
static __device__ inline u16 f2bf(float x){
  unsigned u = __builtin_bit_cast(unsigned, x);
  u += 0x7FFFu + ((u >> 16) & 1u);
  return (u16)(u >> 16);
}
static __device__ inline float bf2f(u16 h){
  unsigned u = ((unsigned)h) << 16;
  return __builtin_bit_cast(float, u);
}

// ---- GAP: mean over HW per (b,c) ----
__global__ __launch_bounds__(256) void k_gap(const float* __restrict__ f, float* __restrict__ gap){
  int bc = blockIdx.x;
  const float* row = f + (size_t)bc * HW_;
  float s = 0.f;
  for (int i = threadIdx.x; i < HW_; i += 256) s += row[i];
  #pragma unroll
  for (int off = 32; off; off >>= 1) s += __shfl_down(s, off);
  __shared__ float red[4];
  int lane = threadIdx.x & 63, wv = threadIdx.x >> 6;
  if (lane == 0) red[wv] = s;
  __syncthreads();
  if (threadIdx.x == 0) gap[bc] = (red[0]+red[1]+red[2]+red[3]) * (1.0f/HW_);
}

// ---- conv1d(k=3)+sigmoid for query/key, rank-1 scores, softmax over i ----
__global__ __launch_bounds__(256) void k_attc(const float* __restrict__ gap,
    const float* __restrict__ wq1, const float* __restrict__ bq1,
    const float* __restrict__ wk1, const float* __restrict__ bk1,
    float* __restrict__ attc){
  int b = blockIdx.x >> 8;
  int j = blockIdx.x & 255;
  int i = threadIdx.x;
  const float* g = gap + b*C_;
  float gm1 = (i > 0)      ? g[i-1] : 0.f;
  float g0  = g[i];
  float gp1 = (i < C_-1)   ? g[i+1] : 0.f;
  float keyv = wk1[0]*gm1 + wk1[1]*g0 + wk1[2]*gp1 + bk1[0];
  keyv = 1.f/(1.f+__expf(-keyv));
  float qm1 = (j > 0)      ? g[j-1] : 0.f;
  float q0  = g[j];
  float qp1 = (j < C_-1)   ? g[j+1] : 0.f;
  float qv = wq1[0]*qm1 + wq1[1]*q0 + wq1[2]*qp1 + bq1[0];
  qv = 1.f/(1.f+__expf(-qv));
  float s = keyv * qv;
  __shared__ float red[256];
  red[i] = s; __syncthreads();
  for (int st = 128; st > 0; st >>= 1){ if (i < st) red[i] = fmaxf(red[i], red[i+st]); __syncthreads(); }
  float mx = red[0]; __syncthreads();
  float e = __expf(s - mx);
  red[i] = e; __syncthreads();
  for (int st = 128; st > 0; st >>= 1){ if (i < st) red[i] += red[i+st]; __syncthreads(); }
  float sum = red[0];
  attc[(size_t)b*C_*C_ + (size_t)i*C_ + j] = e / sum;
}

// ---- q/k/v projections -> bf16 hi/lo split outputs ----
// q,k: [b][pos][e] rows (e contiguous).  v: [b][e][pos] (pos contiguous).
__global__ __launch_bounds__(256) void k_proj2(const float* __restrict__ f,
    const float* __restrict__ wq, const float* __restrict__ bq,
    const float* __restrict__ wk, const float* __restrict__ bk,
    const float* __restrict__ wv, const float* __restrict__ bv,
    u16* __restrict__ qh, u16* __restrict__ qlo,
    u16* __restrict__ kh, u16* __restrict__ klo,
    u16* __restrict__ vh, u16* __restrict__ vlo){
  int b = blockIdx.x, sc = blockIdx.y, mz = blockIdx.z;
  const float* w  = (mz==0) ? wq : ((mz==1) ? wk : wv);
  const float* bi = (mz==0) ? bq : ((mz==1) ? bk : bv);
  int s = sc*256 + threadIdx.x;
  const float* fb = f + (size_t)b*SB_ + s;
  float acc[E_];
  #pragma unroll
  for (int e = 0; e < E_; e++) acc[e] = 0.f;
  for (int cb = 0; cb < 16; cb++){            // runtime loop: keeps code in I$
    float fv[16];
    #pragma unroll
    for (int cc = 0; cc < 16; cc++) fv[cc] = fb[(size_t)(cb*16+cc)*HW_];
    #pragma unroll
    for (int e = 0; e < E_; e++){
      float a = acc[e];
      #pragma unroll
      for (int cc = 0; cc < 16; cc++) a += w[e*C_ + cb*16 + cc] * fv[cc]; // uniform -> s_load
      acc[e] = a;
    }
  }
  if (mz < 2){
    u16* oh = (mz==0 ? qh : kh)  + ((size_t)b*HW_ + s)*E_;
    u16* ol = (mz==0 ? qlo: klo) + ((size_t)b*HW_ + s)*E_;
    for (int e8 = 0; e8 < 8; e8++){
      union { u16 u[8]; uint4 v; } H, L;
      #pragma unroll
      for (int tt = 0; tt < 8; tt++){
        float x = acc[e8*8+tt] + bi[e8*8+tt];
        u16 hb = f2bf(x);
        float hf = bf2f(hb);
        L.u[tt] = f2bf(x - hf);
        H.u[tt] = hb;
      }
      *(uint4*)(oh + e8*8) = H.v;
      *(uint4*)(ol + e8*8) = L.v;
    }
  } else {
    u16* ovh = vh  + (size_t)b*E_*HW_ + s;
    u16* ovl = vlo + (size_t)b*E_*HW_ + s;
    #pragma unroll
    for (int e = 0; e < E_; e++){
      float x = acc[e] + bi[e];
      u16 hb = f2bf(x);
      float hf = bf2f(hb);
      ovh[(size_t)e*HW_] = hb;
      ovl[(size_t)e*HW_] = f2bf(x - hf);
    }
  }
}

// ---- pass 1: l_i = sum_j exp(k_i . q_j), write rl = 1/l. MFMA S-tiles. ----
// grid (B, 72): i-tile = 32 (2 msubs). j-chunks of 32 (2 nsubs). wave w -> (msub=w>>1, nsub=w&1).
__global__ __launch_bounds__(256) void k_stats2(
    const u16* __restrict__ qh, const u16* __restrict__ qlo,
    const u16* __restrict__ kh, const u16* __restrict__ klo,
    float* __restrict__ rl){
  int b = blockIdx.x; int i0 = blockIdx.y*32;
  int t = threadIdx.x, lane = t & 63, w = t >> 6;
  int msub = w >> 1, nsub = w & 1;
  int l15 = lane & 15, g = lane >> 4;
  const size_t bo = (size_t)b*HW_*E_;
  // persistent K A-frags: row i = i0+msub*16+l15, k(e) = ks*32 + g*8 + elem
  const u16* krh = kh  + bo + (size_t)(i0 + msub*16 + l15)*E_ + g*8;
  const u16* krl = klo + bo + (size_t)(i0 + msub*16 + l15)*E_ + g*8;
  bf16x8 kf_h0 = *(const bf16x8*)(krh);
  bf16x8 kf_h1 = *(const bf16x8*)(krh + 32);
  bf16x8 kf_l0 = *(const bf16x8*)(krl);
  bf16x8 kf_l1 = *(const bf16x8*)(krl + 32);
  const u16* qhb = qh  + bo;
  const u16* qlb = qlo + bo;
  float lsum[4] = {0.f, 0.f, 0.f, 0.f};
  for (int jc = 0; jc < 72; jc++){
    int j = jc*32 + nsub*16 + l15;
    const u16* qrh = qhb + (size_t)j*E_ + g*8;
    const u16* qrl = qlb + (size_t)j*E_ + g*8;
    bf16x8 qf_h0 = *(const bf16x8*)(qrh);
    bf16x8 qf_h1 = *(const bf16x8*)(qrh + 32);
    bf16x8 qf_l0 = *(const bf16x8*)(qrl);
    bf16x8 qf_l1 = *(const bf16x8*)(qrl + 32);
    f32x4 acc = {0.f, 0.f, 0.f, 0.f};
    acc = MFMA16(kf_h0, qf_h0, acc);
    acc = MFMA16(kf_h1, qf_h1, acc);
    acc = MFMA16(kf_h0, qf_l0, acc);
    acc = MFMA16(kf_h1, qf_l1, acc);
    acc = MFMA16(kf_l0, qf_h0, acc);
    acc = MFMA16(kf_l1, qf_h1, acc);
    #pragma unroll
    for (int r = 0; r < 4; r++) lsum[r] += __expf(acc[r]);
  }
  // reduce over the 16 lanes (cols j) of each group
  #pragma unroll
  for (int mk = 1; mk < 16; mk <<= 1){
    #pragma unroll
    for (int r = 0; r < 4; r++) lsum[r] += __shfl_xor(lsum[r], mk);
  }
  __shared__ float red[4][16];
  if (l15 == 0){
    #pragma unroll
    for (int r = 0; r < 4; r++) red[w][g*4 + r] = lsum[r];
  }
  __syncthreads();
  if (t < 32){
    int ms = t >> 4, r4 = t & 15;
    float sum = red[2*ms][r4] + red[2*ms+1][r4];
    rl[b*HW_ + i0 + t] = 1.0f / sum;
  }
}

// ---- pass 2: GS[e,j] = sum_i v[e,i]*exp(k_i.q_j)*rl_i via MFMA, P bounced thru LDS ----
// grid (B, 72): j-tile = 32. i-chunks of 32. S: wave->(msub=w>>1, nsub=w&1).
// PV: wave->(epair=w>>1, jsub=w&1), K-dim = 32 = one MFMA k-step.
__global__ __launch_bounds__(256) void k_gs2(
    const u16* __restrict__ qh, const u16* __restrict__ qlo,
    const u16* __restrict__ kh, const u16* __restrict__ klo,
    const u16* __restrict__ vh, const u16* __restrict__ vlo,
    const float* __restrict__ rl, float* __restrict__ gs){
  int b = blockIdx.x; int j0 = blockIdx.y*32;
  int t = threadIdx.x, lane = t & 63, w = t >> 6;
  int l15 = lane & 15, g = lane >> 4;
  int msub = w >> 1, nsub = w & 1;
  __shared__ __align__(16) float rl_lds[HW_];
  __shared__ __align__(16) u16 Ph[2][32][40];  // rows padded to 80B: 2-way banks only
  __shared__ __align__(16) u16 Pl[2][32][40];
  const size_t bo = (size_t)b*HW_*E_;
  for (int n = t; n < HW_; n += 256) rl_lds[n] = rl[b*HW_ + n];
  // persistent Q B-frags: row j = j0+nsub*16+l15
  const u16* qrh = qh  + bo + (size_t)(j0 + nsub*16 + l15)*E_ + g*8;
  const u16* qrl = qlo + bo + (size_t)(j0 + nsub*16 + l15)*E_ + g*8;
  bf16x8 qf_h0 = *(const bf16x8*)(qrh);
  bf16x8 qf_h1 = *(const bf16x8*)(qrh + 32);
  bf16x8 qf_l0 = *(const bf16x8*)(qrl);
  bf16x8 qf_l1 = *(const bf16x8*)(qrl + 32);
  f32x4 gacc[2];
  gacc[0] = (f32x4){0.f,0.f,0.f,0.f};
  gacc[1] = (f32x4){0.f,0.f,0.f,0.f};
  __syncthreads();   // rl_lds ready
  for (int ic = 0; ic < 72; ic++){
    int i0c = ic*32;
    int buf = ic & 1;
    // ---- S phase: subtile (msub, nsub) ----
    const u16* krh = kh  + bo + (size_t)(i0c + msub*16 + l15)*E_ + g*8;
    const u16* krl = klo + bo + (size_t)(i0c + msub*16 + l15)*E_ + g*8;
    bf16x8 kf_h0 = *(const bf16x8*)(krh);
    bf16x8 kf_h1 = *(const bf16x8*)(krh + 32);
    bf16x8 kf_l0 = *(const bf16x8*)(krl);
    bf16x8 kf_l1 = *(const bf16x8*)(krl + 32);
    f32x4 sacc = {0.f,0.f,0.f,0.f};
    sacc = MFMA16(kf_h0, qf_h0, sacc);
    sacc = MFMA16(kf_h1, qf_h1, sacc);
    sacc = MFMA16(kf_h0, qf_l0, sacc);
    sacc = MFMA16(kf_h1, qf_l1, sacc);
    sacc = MFMA16(kf_l0, qf_h0, sacc);
    sacc = MFMA16(kf_l1, qf_h1, sacc);
    // P = exp(s) * rl_i ; rows i = i0c+msub*16+g*4+r, col j = nsub*16+l15
    f32x4 rlv = *(const f32x4*)&rl_lds[i0c + msub*16 + g*4];
    union { u16 u[4]; uint2 v2; } PH, PL;
    #pragma unroll
    for (int r = 0; r < 4; r++){
      float x = __expf(sacc[r]) * rlv[r];
      u16 hb = f2bf(x);
      float hf = bf2f(hb);
      PH.u[r] = hb;
      PL.u[r] = f2bf(x - hf);
    }
    int prow = nsub*16 + l15;
    int pcol = msub*16 + g*4;
    *(uint2*)&Ph[buf][prow][pcol] = PH.v2;
    *(uint2*)&Pl[buf][prow][pcol] = PL.v2;
    __syncthreads();
    // ---- PV phase: waves (epair=w>>1) x (jsub=w&1), 2 esubs each ----
    bf16x8 pf_h = *(const bf16x8*)&Ph[buf][nsub*16 + l15][g*8];
    bf16x8 pf_l = *(const bf16x8*)&Pl[buf][nsub*16 + l15][g*8];
    #pragma unroll
    for (int s2 = 0; s2 < 2; s2++){
      int e = (msub*2 + s2)*16 + l15;
      const u16* vrh = vh  + bo + (size_t)e*HW_ + i0c + g*8;
      const u16* vrl = vlo + bo + (size_t)e*HW_ + i0c + g*8;
      bf16x8 vf_h = *(const bf16x8*)(vrh);
      bf16x8 vf_l = *(const bf16x8*)(vrl);
      gacc[s2] = MFMA16(vf_h, pf_h, gacc[s2]);
      gacc[s2] = MFMA16(vf_h, pf_l, gacc[s2]);
      gacc[s2] = MFMA16(vf_l, pf_h, gacc[s2]);
    }
  }
  // write GS: col j = j0+nsub*16+l15, row e = (msub*2+s2)*16 + g*4 + r
  float* gb = gs + (size_t)b*E_*HW_;
  #pragma unroll
  for (int s2 = 0; s2 < 2; s2++){
    #pragma unroll
    for (int r = 0; r < 4; r++){
      int e = (msub*2 + s2)*16 + g*4 + r;
      gb[(size_t)e*HW_ + j0 + nsub*16 + l15] = gacc[s2][r];
    }
  }
}

// ---- gsout[c,s] = sum_e watt[c,e]*gs[e,s] + batt[c]  (staged in d_out) ----
__global__ __launch_bounds__(256) void k_gsout(const float* __restrict__ gs,
    const float* __restrict__ watt, const float* __restrict__ batt,
    float* __restrict__ gsout){
  int b = blockIdx.x; int sc = blockIdx.y; int cc0 = blockIdx.z * 16;
  int s = sc*256 + threadIdx.x;
  __shared__ float lw[1024];
  for (int n = threadIdx.x; n < 1024; n += 256) lw[n] = watt[cc0*E_ + n];
  __syncthreads();
  const float* gb = gs + (size_t)b*E_*HW_ + s;
  float acc[16];
  #pragma unroll
  for (int x = 0; x < 16; x++) acc[x] = 0.f;
  for (int e = 0; e < E_; e++){
    float gv = gb[(size_t)e*HW_];
    #pragma unroll
    for (int x = 0; x < 16; x++) acc[x] += lw[x*64 + e] * gv;
  }
  float* ob = gsout + (size_t)b*SB_ + (size_t)cc0*HW_ + s;
  #pragma unroll
  for (int x = 0; x < 16; x++) ob[(size_t)x*HW_] = acc[x] + batt[cc0 + x];
}

// ---- final: gc GEMM (V @ att_c) fused with out = f*gc*(gsout+1), in-place on d_out ----
__global__ __launch_bounds__(256) void k_final(const float* __restrict__ f,
    const float* __restrict__ attc, const float* __restrict__ gsout,
    float* __restrict__ out){
  int b = blockIdx.x; int p0 = blockIdx.y * 64;
  int j = threadIdx.x;
  __shared__ float A[16384];
  const float* fb = f + (size_t)b*SB_ + (size_t)p0*C_;
  for (int n = j; n < 16384; n += 256) A[n] = fb[n];
  __syncthreads();
  const float* ab = attc + (size_t)b*C_*C_;
  float acc[64];
  #pragma unroll
  for (int p = 0; p < 64; p++) acc[p] = 0.f;
  for (int i = 0; i < C_; i++){
    float bv = ab[(size_t)i*C_ + j];
    #pragma unroll
    for (int p = 0; p < 64; p++) acc[p] += A[p*256 + i] * bv;
  }
  const float* gb = gsout + (size_t)b*SB_ + (size_t)p0*C_;
  float* ob = out + (size_t)b*SB_ + (size_t)p0*C_;
  #pragma unroll
  for (int p = 0; p < 64; p++){
    float fx = A[p*256 + j];
    float g  = gb[p*256 + j];
    ob[p*256 + j] = acc[p] * fx * (g + 1.f);
  }
}

extern "C" void kernel_launch(void* const* d_in, const int* in_sizes, int n_in,
                              void* d_out, int out_size, void* d_ws, size_t ws_size,
                              hipStream_t stream){
  const float* f    = (const float*)d_in[0];
  const float* wq1  = (const float*)d_in[1];
  const float* bq1  = (const float*)d_in[2];
  const float* wk1  = (const float*)d_in[3];
  const float* bk1  = (const float*)d_in[4];
  const float* wq2  = (const float*)d_in[5];
  const float* bq2  = (const float*)d_in[6];
  const float* wk2  = (const float*)d_in[7];
  const float* bk2  = (const float*)d_in[8];
  const float* wv2  = (const float*)d_in[9];
  const float* bv2  = (const float*)d_in[10];
  const float* watt = (const float*)d_in[11];
  const float* batt = (const float*)d_in[12];
  float* out = (float*)d_out;
  char* W = (char*)d_ws;

  // byte offsets (all 16B-aligned); total = 21,053,440 B
  float* gap  = (float*)(W + 0);          //    8192 B
  float* attc = (float*)(W + 8192);       // 2097152 B
  float* rl   = (float*)(W + 2105344);    //   73728 B
  float* gs   = (float*)(W + 2179072);    // 4718592 B
  u16* qh  = (u16*)(W + 6897664);         // 2359296 B each below
  u16* qlo = (u16*)(W + 9256960);
  u16* kh  = (u16*)(W + 11616256);
  u16* klo = (u16*)(W + 13975552);
  u16* vh  = (u16*)(W + 16334848);
  u16* vlo = (u16*)(W + 18694144);

  k_gap   <<<B_*C_,           256, 0, stream>>>(f, gap);
  k_attc  <<<B_*C_,           256, 0, stream>>>(gap, wq1, bq1, wk1, bk1, attc);
  k_proj2 <<<dim3(B_, 9, 3),  256, 0, stream>>>(f, wq2, bq2, wk2, bk2, wv2, bv2,
                                                qh, qlo, kh, klo, vh, vlo);
  k_stats2<<<dim3(B_, 72),    256, 0, stream>>>(qh, qlo, kh, klo, rl);
  k_gs2   <<<dim3(B_, 72),    256, 0, stream>>>(qh, qlo, kh, klo, vh, vlo, rl, gs);
  k_gsout <<<dim3(B_, 9, 16), 256, 0, stream>>>(gs, watt, batt, out);
  k_final <<<dim3(B_, 36),    256, 0, stream>>>(f, attc, out, out);
}

// Round 3
// 620.255 us; speedup vs baseline: 2.8148x; 1.1842x over previous
//
#include <hip/hip_runtime.h>

#define B_ 8
#define C_ 256
#define HW_ 2304
#define E_ 64
#define SB_ (C_*HW_)  // 589824 floats per batch

typedef unsigned short u16;
typedef __attribute__((ext_vector_type(8))) __bf16 bf16x8;
typedef __attribute__((ext_vector_type(4))) float f32x4;
#define MFMA16(a,b,c) __builtin_amdgcn_mfma_f32_16x16x32_bf16(a,b,c,0,0,0)

// fp32 -> bf16 RNE via integer ops
static __device__ inline u16 f2bf(float x){
  unsigned u = __builtin_bit_cast(unsigned, x);
  u += 0x7FFFu + ((u >> 16) & 1u);
  return (u16)(u >> 16);
}
static __device__ inline float bf2f(u16 h){
  unsigned u = ((unsigned)h) << 16;
  return __builtin_bit_cast(float, u);
}

// ---- GAP: mean over HW per (b,c) ----
__global__ __launch_bounds__(256) void k_gap(const float* __restrict__ f, float* __restrict__ gap){
  int bc = blockIdx.x;
  const float* row = f + (size_t)bc * HW_;
  float s = 0.f;
  for (int i = threadIdx.x; i < HW_; i += 256) s += row[i];
  #pragma unroll
  for (int off = 32; off; off >>= 1) s += __shfl_down(s, off);
  __shared__ float red[4];
  int lane = threadIdx.x & 63, wv = threadIdx.x >> 6;
  if (lane == 0) red[wv] = s;
  __syncthreads();
  if (threadIdx.x == 0) gap[bc] = (red[0]+red[1]+red[2]+red[3]) * (1.0f/HW_);
}

// ---- conv1d(k=3)+sigmoid for query/key, rank-1 scores, softmax over i ----
__global__ __launch_bounds__(256) void k_attc(const float* __restrict__ gap,
    const float* __restrict__ wq1, const float* __restrict__ bq1,
    const float* __restrict__ wk1, const float* __restrict__ bk1,
    float* __restrict__ attc){
  int b = blockIdx.x >> 8;
  int j = blockIdx.x & 255;
  int i = threadIdx.x;
  const float* g = gap + b*C_;
  float gm1 = (i > 0)      ? g[i-1] : 0.f;
  float g0  = g[i];
  float gp1 = (i < C_-1)   ? g[i+1] : 0.f;
  float keyv = wk1[0]*gm1 + wk1[1]*g0 + wk1[2]*gp1 + bk1[0];
  keyv = 1.f/(1.f+__expf(-keyv));
  float qm1 = (j > 0)      ? g[j-1] : 0.f;
  float q0  = g[j];
  float qp1 = (j < C_-1)   ? g[j+1] : 0.f;
  float qv = wq1[0]*qm1 + wq1[1]*q0 + wq1[2]*qp1 + bq1[0];
  qv = 1.f/(1.f+__expf(-qv));
  float s = keyv * qv;
  __shared__ float red[256];
  red[i] = s; __syncthreads();
  for (int st = 128; st > 0; st >>= 1){ if (i < st) red[i] = fmaxf(red[i], red[i+st]); __syncthreads(); }
  float mx = red[0]; __syncthreads();
  float e = __expf(s - mx);
  red[i] = e; __syncthreads();
  for (int st = 128; st > 0; st >>= 1){ if (i < st) red[i] += red[i+st]; __syncthreads(); }
  float sum = red[0];
  attc[(size_t)b*C_*C_ + (size_t)i*C_ + j] = e / sum;
}

// ---- q/k/v projections -> bf16 hi/lo; F tile staged once in LDS ----
// grid (B, 36): s-tile of 64. 256 threads = 4 waves; wave = e-group of 16.
// q,k: [b][pos][e] (e contiguous).  v: [b][e][pos] (pos contiguous).
__global__ __launch_bounds__(256) void k_proj3(const float* __restrict__ f,
    const float* __restrict__ wq, const float* __restrict__ bq,
    const float* __restrict__ wk, const float* __restrict__ bk,
    const float* __restrict__ wv, const float* __restrict__ bv,
    u16* __restrict__ qh, u16* __restrict__ qlo,
    u16* __restrict__ kh, u16* __restrict__ klo,
    u16* __restrict__ vh, u16* __restrict__ vlo){
  int b = blockIdx.x; int s0 = blockIdx.y*64;
  int t = threadIdx.x;
  int sl = t & 63;      // position within tile (lane)
  int eg = t >> 6;      // e-group (wave)
  __shared__ __align__(16) float F[C_*64];   // [c][sl], 64KB
  const float* fb = f + (size_t)b*SB_ + s0;
  #pragma unroll
  for (int it = 0; it < 16; it++){
    int n4 = t*4 + it*1024;
    int c = n4 >> 6, ss = n4 & 63;
    *(float4*)&F[n4] = *(const float4*)&fb[(size_t)c*HW_ + ss];
  }
  __syncthreads();
  int s = s0 + sl;
  int e0 = eg*16;
  for (int mz = 0; mz < 3; mz++){
    const float* w  = (mz==0) ? wq : ((mz==1) ? wk : wv);
    const float* bi = (mz==0) ? bq : ((mz==1) ? bk : bv);
    float acc[16];
    #pragma unroll
    for (int e = 0; e < 16; e++) acc[e] = 0.f;
    for (int c4 = 0; c4 < 64; c4++){          // runtime loop, 4-unrolled inside
      float fv[4];
      #pragma unroll
      for (int u = 0; u < 4; u++) fv[u] = F[(c4*4+u)*64 + sl];
      #pragma unroll
      for (int e = 0; e < 16; e++){
        float a = acc[e];
        #pragma unroll
        for (int u = 0; u < 4; u++) a += w[(e0+e)*C_ + c4*4 + u] * fv[u];
        acc[e] = a;
      }
    }
    if (mz < 2){
      u16* oh = (mz==0 ? qh : kh)  + ((size_t)b*HW_ + s)*E_ + e0;
      u16* ol = (mz==0 ? qlo: klo) + ((size_t)b*HW_ + s)*E_ + e0;
      union { u16 u[16]; uint4 v[2]; } H, L;
      #pragma unroll
      for (int tt = 0; tt < 16; tt++){
        float x = acc[tt] + bi[e0+tt];
        u16 hb = f2bf(x);
        float hf = bf2f(hb);
        L.u[tt] = f2bf(x - hf);
        H.u[tt] = hb;
      }
      *(uint4*)(oh)     = H.v[0];
      *(uint4*)(oh + 8) = H.v[1];
      *(uint4*)(ol)     = L.v[0];
      *(uint4*)(ol + 8) = L.v[1];
    } else {
      u16* ovh = vh  + (size_t)b*E_*HW_ + s;
      u16* ovl = vlo + (size_t)b*E_*HW_ + s;
      #pragma unroll
      for (int tt = 0; tt < 16; tt++){
        float x = acc[tt] + bi[e0+tt];
        u16 hb = f2bf(x);
        float hf = bf2f(hb);
        ovh[(size_t)(e0+tt)*HW_] = hb;
        ovl[(size_t)(e0+tt)*HW_] = f2bf(x - hf);
      }
    }
  }
}

// ---- pass 1: l_i = sum_j exp(k_i . q_j), write rl = 1/l. MFMA S-tiles. ----
__global__ __launch_bounds__(256) void k_stats2(
    const u16* __restrict__ qh, const u16* __restrict__ qlo,
    const u16* __restrict__ kh, const u16* __restrict__ klo,
    float* __restrict__ rl){
  int b = blockIdx.x; int i0 = blockIdx.y*32;
  int t = threadIdx.x, lane = t & 63, w = t >> 6;
  int msub = w >> 1, nsub = w & 1;
  int l15 = lane & 15, g = lane >> 4;
  const size_t bo = (size_t)b*HW_*E_;
  const u16* krh = kh  + bo + (size_t)(i0 + msub*16 + l15)*E_ + g*8;
  const u16* krl = klo + bo + (size_t)(i0 + msub*16 + l15)*E_ + g*8;
  bf16x8 kf_h0 = *(const bf16x8*)(krh);
  bf16x8 kf_h1 = *(const bf16x8*)(krh + 32);
  bf16x8 kf_l0 = *(const bf16x8*)(krl);
  bf16x8 kf_l1 = *(const bf16x8*)(krl + 32);
  const u16* qhb = qh  + bo;
  const u16* qlb = qlo + bo;
  float lsum[4] = {0.f, 0.f, 0.f, 0.f};
  for (int jc = 0; jc < 72; jc++){
    int j = jc*32 + nsub*16 + l15;
    const u16* qrh = qhb + (size_t)j*E_ + g*8;
    const u16* qrl = qlb + (size_t)j*E_ + g*8;
    bf16x8 qf_h0 = *(const bf16x8*)(qrh);
    bf16x8 qf_h1 = *(const bf16x8*)(qrh + 32);
    bf16x8 qf_l0 = *(const bf16x8*)(qrl);
    bf16x8 qf_l1 = *(const bf16x8*)(qrl + 32);
    f32x4 acc = {0.f, 0.f, 0.f, 0.f};
    acc = MFMA16(kf_h0, qf_h0, acc);
    acc = MFMA16(kf_h1, qf_h1, acc);
    acc = MFMA16(kf_h0, qf_l0, acc);
    acc = MFMA16(kf_h1, qf_l1, acc);
    acc = MFMA16(kf_l0, qf_h0, acc);
    acc = MFMA16(kf_l1, qf_h1, acc);
    #pragma unroll
    for (int r = 0; r < 4; r++) lsum[r] += __expf(acc[r]);
  }
  #pragma unroll
  for (int mk = 1; mk < 16; mk <<= 1){
    #pragma unroll
    for (int r = 0; r < 4; r++) lsum[r] += __shfl_xor(lsum[r], mk);
  }
  __shared__ float red[4][16];
  if (l15 == 0){
    #pragma unroll
    for (int r = 0; r < 4; r++) red[w][g*4 + r] = lsum[r];
  }
  __syncthreads();
  if (t < 32){
    int ms = t >> 4, r4 = t & 15;
    float sum = red[2*ms][r4] + red[2*ms+1][r4];
    rl[b*HW_ + i0 + t] = 1.0f / sum;
  }
}

// ---- pass 2: GS[e,j] = sum_i v[e,i]*exp(k_i.q_j)*rl_i via MFMA ----
__global__ __launch_bounds__(256) void k_gs2(
    const u16* __restrict__ qh, const u16* __restrict__ qlo,
    const u16* __restrict__ kh, const u16* __restrict__ klo,
    const u16* __restrict__ vh, const u16* __restrict__ vlo,
    const float* __restrict__ rl, float* __restrict__ gs){
  int b = blockIdx.x; int j0 = blockIdx.y*32;
  int t = threadIdx.x, lane = t & 63, w = t >> 6;
  int l15 = lane & 15, g = lane >> 4;
  int msub = w >> 1, nsub = w & 1;
  __shared__ __align__(16) float rl_lds[HW_];
  __shared__ __align__(16) u16 Ph[2][32][40];
  __shared__ __align__(16) u16 Pl[2][32][40];
  const size_t bo = (size_t)b*HW_*E_;
  for (int n = t; n < HW_; n += 256) rl_lds[n] = rl[b*HW_ + n];
  const u16* qrh = qh  + bo + (size_t)(j0 + nsub*16 + l15)*E_ + g*8;
  const u16* qrl = qlo + bo + (size_t)(j0 + nsub*16 + l15)*E_ + g*8;
  bf16x8 qf_h0 = *(const bf16x8*)(qrh);
  bf16x8 qf_h1 = *(const bf16x8*)(qrh + 32);
  bf16x8 qf_l0 = *(const bf16x8*)(qrl);
  bf16x8 qf_l1 = *(const bf16x8*)(qrl + 32);
  f32x4 gacc[2];
  gacc[0] = (f32x4){0.f,0.f,0.f,0.f};
  gacc[1] = (f32x4){0.f,0.f,0.f,0.f};
  __syncthreads();
  for (int ic = 0; ic < 72; ic++){
    int i0c = ic*32;
    int buf = ic & 1;
    const u16* krh = kh  + bo + (size_t)(i0c + msub*16 + l15)*E_ + g*8;
    const u16* krl = klo + bo + (size_t)(i0c + msub*16 + l15)*E_ + g*8;
    bf16x8 kf_h0 = *(const bf16x8*)(krh);
    bf16x8 kf_h1 = *(const bf16x8*)(krh + 32);
    bf16x8 kf_l0 = *(const bf16x8*)(krl);
    bf16x8 kf_l1 = *(const bf16x8*)(krl + 32);
    f32x4 sacc = {0.f,0.f,0.f,0.f};
    sacc = MFMA16(kf_h0, qf_h0, sacc);
    sacc = MFMA16(kf_h1, qf_h1, sacc);
    sacc = MFMA16(kf_h0, qf_l0, sacc);
    sacc = MFMA16(kf_h1, qf_l1, sacc);
    sacc = MFMA16(kf_l0, qf_h0, sacc);
    sacc = MFMA16(kf_l1, qf_h1, sacc);
    f32x4 rlv = *(const f32x4*)&rl_lds[i0c + msub*16 + g*4];
    union { u16 u[4]; uint2 v2; } PH, PL;
    #pragma unroll
    for (int r = 0; r < 4; r++){
      float x = __expf(sacc[r]) * rlv[r];
      u16 hb = f2bf(x);
      float hf = bf2f(hb);
      PH.u[r] = hb;
      PL.u[r] = f2bf(x - hf);
    }
    int prow = nsub*16 + l15;
    int pcol = msub*16 + g*4;
    *(uint2*)&Ph[buf][prow][pcol] = PH.v2;
    *(uint2*)&Pl[buf][prow][pcol] = PL.v2;
    __syncthreads();
    bf16x8 pf_h = *(const bf16x8*)&Ph[buf][nsub*16 + l15][g*8];
    bf16x8 pf_l = *(const bf16x8*)&Pl[buf][nsub*16 + l15][g*8];
    #pragma unroll
    for (int s2 = 0; s2 < 2; s2++){
      int e = (msub*2 + s2)*16 + l15;
      const u16* vrh = vh  + bo + (size_t)e*HW_ + i0c + g*8;
      const u16* vrl = vlo + bo + (size_t)e*HW_ + i0c + g*8;
      bf16x8 vf_h = *(const bf16x8*)(vrh);
      bf16x8 vf_l = *(const bf16x8*)(vrl);
      gacc[s2] = MFMA16(vf_h, pf_h, gacc[s2]);
      gacc[s2] = MFMA16(vf_h, pf_l, gacc[s2]);
      gacc[s2] = MFMA16(vf_l, pf_h, gacc[s2]);
    }
  }
  float* gb = gs + (size_t)b*E_*HW_;
  #pragma unroll
  for (int s2 = 0; s2 < 2; s2++){
    #pragma unroll
    for (int r = 0; r < 4; r++){
      int e = (msub*2 + s2)*16 + g*4 + r;
      gb[(size_t)e*HW_ + j0 + nsub*16 + l15] = gacc[s2][r];
    }
  }
}

// ---- gsout[c,s] = sum_e watt[c,e]*gs[e,s] + batt[c]  (staged in d_out) ----
__global__ __launch_bounds__(256) void k_gsout(const float* __restrict__ gs,
    const float* __restrict__ watt, const float* __restrict__ batt,
    float* __restrict__ gsout){
  int b = blockIdx.x; int sc = blockIdx.y; int cc0 = blockIdx.z * 16;
  int s = sc*256 + threadIdx.x;
  __shared__ float lw[1024];
  for (int n = threadIdx.x; n < 1024; n += 256) lw[n] = watt[cc0*E_ + n];
  __syncthreads();
  const float* gb = gs + (size_t)b*E_*HW_ + s;
  float acc[16];
  #pragma unroll
  for (int x = 0; x < 16; x++) acc[x] = 0.f;
  for (int e = 0; e < E_; e++){
    float gv = gb[(size_t)e*HW_];
    #pragma unroll
    for (int x = 0; x < 16; x++) acc[x] += lw[x*64 + e] * gv;
  }
  float* ob = gsout + (size_t)b*SB_ + (size_t)cc0*HW_ + s;
  #pragma unroll
  for (int x = 0; x < 16; x++) ob[(size_t)x*HW_] = acc[x] + batt[cc0 + x];
}

// ---- final: gc GEMM (V @ att_c) fused with out = f*gc*(gsout+1), in-place on d_out ----
__global__ __launch_bounds__(256) void k_final(const float* __restrict__ f,
    const float* __restrict__ attc, const float* __restrict__ gsout,
    float* __restrict__ out){
  int b = blockIdx.x; int p0 = blockIdx.y * 64;
  int j = threadIdx.x;
  __shared__ float A[16384];
  const float* fb = f + (size_t)b*SB_ + (size_t)p0*C_;
  for (int n = j; n < 16384; n += 256) A[n] = fb[n];
  __syncthreads();
  const float* ab = attc + (size_t)b*C_*C_;
  float acc[64];
  #pragma unroll
  for (int p = 0; p < 64; p++) acc[p] = 0.f;
  for (int i = 0; i < C_; i++){
    float bv = ab[(size_t)i*C_ + j];
    #pragma unroll
    for (int p = 0; p < 64; p++) acc[p] += A[p*256 + i] * bv;
  }
  const float* gb = gsout + (size_t)b*SB_ + (size_t)p0*C_;
  float* ob = out + (size_t)b*SB_ + (size_t)p0*C_;
  #pragma unroll
  for (int p = 0; p < 64; p++){
    float fx = A[p*256 + j];
    float g  = gb[p*256 + j];
    ob[p*256 + j] = acc[p] * fx * (g + 1.f);
  }
}

extern "C" void kernel_launch(void* const* d_in, const int* in_sizes, int n_in,
                              void* d_out, int out_size, void* d_ws, size_t ws_size,
                              hipStream_t stream){
  const float* f    = (const float*)d_in[0];
  const float* wq1  = (const float*)d_in[1];
  const float* bq1  = (const float*)d_in[2];
  const float* wk1  = (const float*)d_in[3];
  const float* bk1  = (const float*)d_in[4];
  const float* wq2  = (const float*)d_in[5];
  const float* bq2  = (const float*)d_in[6];
  const float* wk2  = (const float*)d_in[7];
  const float* bk2  = (const float*)d_in[8];
  const float* wv2  = (const float*)d_in[9];
  const float* bv2  = (const float*)d_in[10];
  const float* watt = (const float*)d_in[11];
  const float* batt = (const float*)d_in[12];
  float* out = (float*)d_out;
  char* W = (char*)d_ws;

  float* gap  = (float*)(W + 0);          //    8192 B
  float* attc = (float*)(W + 8192);       // 2097152 B
  float* rl   = (float*)(W + 2105344);    //   73728 B
  float* gs   = (float*)(W + 2179072);    // 4718592 B
  u16* qh  = (u16*)(W + 6897664);         // 2359296 B each below
  u16* qlo = (u16*)(W + 9256960);
  u16* kh  = (u16*)(W + 11616256);
  u16* klo = (u16*)(W + 13975552);
  u16* vh  = (u16*)(W + 16334848);
  u16* vlo = (u16*)(W + 18694144);

  k_gap   <<<B_*C_,           256, 0, stream>>>(f, gap);
  k_attc  <<<B_*C_,           256, 0, stream>>>(gap, wq1, bq1, wk1, bk1, attc);
  k_proj3 <<<dim3(B_, 36),    256, 0, stream>>>(f, wq2, bq2, wk2, bk2, wv2, bv2,
                                                qh, qlo, kh, klo, vh, vlo);
  k_stats2<<<dim3(B_, 72),    256, 0, stream>>>(qh, qlo, kh, klo, rl);
  k_gs2   <<<dim3(B_, 72),    256, 0, stream>>>(qh, qlo, kh, klo, vh, vlo, rl, gs);
  k_gsout <<<dim3(B_, 9, 16), 256, 0, stream>>>(gs, watt, batt, out);
  k_final <<<dim3(B_, 36),    256, 0, stream>>>(f, attc, out, out);
}

// Round 4
// 502.916 us; speedup vs baseline: 3.4715x; 1.2333x over previous
//
#include <hip/hip_runtime.h>

#define B_ 8
#define C_ 256
#define HW_ 2304
#define E_ 64
#define SB_ (C_*HW_)  // 589824 floats per batch

typedef unsigned short u16;
typedef __attribute__((ext_vector_type(8))) __bf16 bf16x8;
typedef __attribute__((ext_vector_type(4))) float f32x4;
#define MFMA16(a,b,c) __builtin_amdgcn_mfma_f32_16x16x32_bf16(a,b,c,0,0,0)

// fp32 -> bf16 RNE via integer ops
static __device__ inline u16 f2bf(float x){
  unsigned u = __builtin_bit_cast(unsigned, x);
  u += 0x7FFFu + ((u >> 16) & 1u);
  return (u16)(u >> 16);
}
static __device__ inline float bf2f(u16 h){
  unsigned u = ((unsigned)h) << 16;
  return __builtin_bit_cast(float, u);
}

// ---- GAP: mean over HW per (b,c) ----
__global__ __launch_bounds__(256) void k_gap(const float* __restrict__ f, float* __restrict__ gap){
  int bc = blockIdx.x;
  const float* row = f + (size_t)bc * HW_;
  float s = 0.f;
  for (int i = threadIdx.x; i < HW_; i += 256) s += row[i];
  #pragma unroll
  for (int off = 32; off; off >>= 1) s += __shfl_down(s, off);
  __shared__ float red[4];
  int lane = threadIdx.x & 63, wv = threadIdx.x >> 6;
  if (lane == 0) red[wv] = s;
  __syncthreads();
  if (threadIdx.x == 0) gap[bc] = (red[0]+red[1]+red[2]+red[3]) * (1.0f/HW_);
}

// ---- conv1d(k=3)+sigmoid, rank-1 scores, softmax over i ----
__global__ __launch_bounds__(256) void k_attc(const float* __restrict__ gap,
    const float* __restrict__ wq1, const float* __restrict__ bq1,
    const float* __restrict__ wk1, const float* __restrict__ bk1,
    float* __restrict__ attc){
  int b = blockIdx.x >> 8;
  int j = blockIdx.x & 255;
  int i = threadIdx.x;
  const float* g = gap + b*C_;
  float gm1 = (i > 0)      ? g[i-1] : 0.f;
  float g0  = g[i];
  float gp1 = (i < C_-1)   ? g[i+1] : 0.f;
  float keyv = wk1[0]*gm1 + wk1[1]*g0 + wk1[2]*gp1 + bk1[0];
  keyv = 1.f/(1.f+__expf(-keyv));
  float qm1 = (j > 0)      ? g[j-1] : 0.f;
  float q0  = g[j];
  float qp1 = (j < C_-1)   ? g[j+1] : 0.f;
  float qv = wq1[0]*qm1 + wq1[1]*q0 + wq1[2]*qp1 + bq1[0];
  qv = 1.f/(1.f+__expf(-qv));
  float s = keyv * qv;
  __shared__ float red[256];
  red[i] = s; __syncthreads();
  for (int st = 128; st > 0; st >>= 1){ if (i < st) red[i] = fmaxf(red[i], red[i+st]); __syncthreads(); }
  float mx = red[0]; __syncthreads();
  float e = __expf(s - mx);
  red[i] = e; __syncthreads();
  for (int st = 128; st > 0; st >>= 1){ if (i < st) red[i] += red[i+st]; __syncthreads(); }
  float sum = red[0];
  attc[(size_t)b*C_*C_ + (size_t)i*C_ + j] = e / sum;
}

// ---- q/k/v projections -> bf16 hi/lo; F tile in LDS; one matrix per block (z) ----
// grid (B, 36, 3). 256 threads = 4 waves; wave = e-group of 16.
__global__ __launch_bounds__(256) void k_proj3(const float* __restrict__ f,
    const float* __restrict__ wq, const float* __restrict__ bq,
    const float* __restrict__ wk, const float* __restrict__ bk,
    const float* __restrict__ wv, const float* __restrict__ bv,
    u16* __restrict__ qh, u16* __restrict__ qlo,
    u16* __restrict__ kh, u16* __restrict__ klo,
    u16* __restrict__ vh, u16* __restrict__ vlo){
  int b = blockIdx.x; int s0 = blockIdx.y*64; int mz = blockIdx.z;
  int t = threadIdx.x;
  int sl = t & 63;
  int eg = t >> 6;
  __shared__ __align__(16) float F[C_*64];   // [c][sl], 64KB
  const float* fb = f + (size_t)b*SB_ + s0;
  #pragma unroll
  for (int it = 0; it < 16; it++){
    int n4 = t*4 + it*1024;
    int c = n4 >> 6, ss = n4 & 63;
    *(float4*)&F[n4] = *(const float4*)&fb[(size_t)c*HW_ + ss];
  }
  __syncthreads();
  int s = s0 + sl;
  int e0 = eg*16;
  const float* w  = (mz==0) ? wq : ((mz==1) ? wk : wv);
  const float* bi = (mz==0) ? bq : ((mz==1) ? bk : bv);
  float acc[16];
  #pragma unroll
  for (int e = 0; e < 16; e++) acc[e] = 0.f;
  for (int c4 = 0; c4 < 64; c4++){
    float fv[4];
    #pragma unroll
    for (int u = 0; u < 4; u++) fv[u] = F[(c4*4+u)*64 + sl];
    #pragma unroll
    for (int e = 0; e < 16; e++){
      float a = acc[e];
      #pragma unroll
      for (int u = 0; u < 4; u++) a += w[(e0+e)*C_ + c4*4 + u] * fv[u];
      acc[e] = a;
    }
  }
  if (mz < 2){
    u16* oh = (mz==0 ? qh : kh)  + ((size_t)b*HW_ + s)*E_ + e0;
    u16* ol = (mz==0 ? qlo: klo) + ((size_t)b*HW_ + s)*E_ + e0;
    union { u16 u[16]; uint4 v[2]; } H, L;
    #pragma unroll
    for (int tt = 0; tt < 16; tt++){
      float x = acc[tt] + bi[e0+tt];
      u16 hb = f2bf(x);
      float hf = bf2f(hb);
      L.u[tt] = f2bf(x - hf);
      H.u[tt] = hb;
    }
    *(uint4*)(oh)     = H.v[0];
    *(uint4*)(oh + 8) = H.v[1];
    *(uint4*)(ol)     = L.v[0];
    *(uint4*)(ol + 8) = L.v[1];
  } else {
    u16* ovh = vh  + (size_t)b*E_*HW_ + s;
    u16* ovl = vlo + (size_t)b*E_*HW_ + s;
    #pragma unroll
    for (int tt = 0; tt < 16; tt++){
      float x = acc[tt] + bi[e0+tt];
      u16 hb = f2bf(x);
      float hf = bf2f(hb);
      ovh[(size_t)(e0+tt)*HW_] = hb;
      ovl[(size_t)(e0+tt)*HW_] = f2bf(x - hf);
    }
  }
}

// ---- pass 1: partial row sums l_i over half the j range. Single-wave blocks. ----
// grid (B, 144, 2): i-tile 16 at blockIdx.y, j range = z*1152..+1152.
__global__ __launch_bounds__(64) void k_stats3(
    const u16* __restrict__ qh, const u16* __restrict__ qlo,
    const u16* __restrict__ kh, const u16* __restrict__ klo,
    float* __restrict__ lpart){
  int b = blockIdx.x; int i0 = blockIdx.y*16; int jz = blockIdx.z;
  int lane = threadIdx.x; int l15 = lane & 15, g = lane >> 4;
  const size_t bo = (size_t)b*HW_*E_;
  // persistent K A-frags: row i = i0 + l15
  const u16* krh = kh  + bo + (size_t)(i0 + l15)*E_ + g*8;
  const u16* krl = klo + bo + (size_t)(i0 + l15)*E_ + g*8;
  bf16x8 kf_h0 = *(const bf16x8*)(krh);
  bf16x8 kf_h1 = *(const bf16x8*)(krh + 32);
  bf16x8 kf_l0 = *(const bf16x8*)(krl);
  bf16x8 kf_l1 = *(const bf16x8*)(krl + 32);
  const u16* qhb = qh  + bo;
  const u16* qlb = qlo + bo;
  float lsum[4] = {0.f, 0.f, 0.f, 0.f};
  for (int jc = 0; jc < 36; jc++){
    int j = jz*1152 + jc*32;
    #pragma unroll
    for (int nsub = 0; nsub < 2; nsub++){
      const u16* qrh = qhb + (size_t)(j + nsub*16 + l15)*E_ + g*8;
      const u16* qrl = qlb + (size_t)(j + nsub*16 + l15)*E_ + g*8;
      bf16x8 qf_h0 = *(const bf16x8*)(qrh);
      bf16x8 qf_h1 = *(const bf16x8*)(qrh + 32);
      bf16x8 qf_l0 = *(const bf16x8*)(qrl);
      bf16x8 qf_l1 = *(const bf16x8*)(qrl + 32);
      f32x4 acc = {0.f, 0.f, 0.f, 0.f};
      acc = MFMA16(kf_h0, qf_h0, acc);
      acc = MFMA16(kf_h1, qf_h1, acc);
      acc = MFMA16(kf_h0, qf_l0, acc);
      acc = MFMA16(kf_h1, qf_l1, acc);
      acc = MFMA16(kf_l0, qf_h0, acc);
      acc = MFMA16(kf_l1, qf_h1, acc);
      #pragma unroll
      for (int r = 0; r < 4; r++) lsum[r] += __expf(acc[r]);
    }
  }
  // reduce over 16 cols (l15) within each g-group
  #pragma unroll
  for (int mk = 1; mk < 16; mk <<= 1){
    #pragma unroll
    for (int r = 0; r < 4; r++) lsum[r] += __shfl_xor(lsum[r], mk);
  }
  if (l15 == 0){
    float* lp = lpart + (size_t)jz*B_*HW_ + b*HW_ + i0 + g*4;
    #pragma unroll
    for (int r = 0; r < 4; r++) lp[r] = lsum[r];
  }
}

// ---- rl = 1/(l0+l1) ----
__global__ __launch_bounds__(256) void k_rl(const float* __restrict__ lpart, float* __restrict__ rl){
  int i = blockIdx.x*256 + threadIdx.x;
  rl[i] = 1.0f / (lpart[i] + lpart[(size_t)B_*HW_ + i]);
}

// ---- pass 2: partial GS over half the i range. Single-wave blocks, private LDS P. ----
// grid (B, 144, 2): j-tile 16 at blockIdx.y, i range = z*1152..+1152 (36 chunks of 32).
__global__ __launch_bounds__(64) void k_gs3(
    const u16* __restrict__ qh, const u16* __restrict__ qlo,
    const u16* __restrict__ kh, const u16* __restrict__ klo,
    const u16* __restrict__ vh, const u16* __restrict__ vlo,
    const float* __restrict__ rl, float* __restrict__ gsp){
  int b = blockIdx.x; int j0 = blockIdx.y*16; int iz = blockIdx.z;
  int lane = threadIdx.x; int l15 = lane & 15, g = lane >> 4;
  // P tiles: [buf][j(16) rows of 64B][i(32) u16], XOR-swizzled by ((j&3)<<4)
  __shared__ __align__(16) u16 Ph[2][16*32];
  __shared__ __align__(16) u16 Pl[2][16*32];
  const size_t bo = (size_t)b*HW_*E_;
  // persistent Q B-frags: col j = j0 + l15
  const u16* qrh = qh  + bo + (size_t)(j0 + l15)*E_ + g*8;
  const u16* qrl = qlo + bo + (size_t)(j0 + l15)*E_ + g*8;
  bf16x8 qf_h0 = *(const bf16x8*)(qrh);
  bf16x8 qf_h1 = *(const bf16x8*)(qrh + 32);
  bf16x8 qf_l0 = *(const bf16x8*)(qrl);
  bf16x8 qf_l1 = *(const bf16x8*)(qrl + 32);
  f32x4 gacc[4];
  #pragma unroll
  for (int es = 0; es < 4; es++) gacc[es] = (f32x4){0.f,0.f,0.f,0.f};
  const int swz = (l15 & 3) << 4;          // row(j)=l15 for both P writes and P reads
  const float* rlb = rl + b*HW_;
  for (int ic = 0; ic < 36; ic++){
    int i0c = iz*1152 + ic*32;
    int buf = ic & 1;
    char* PhB = (char*)&Ph[buf][0];
    char* PlB = (char*)&Pl[buf][0];
    #pragma unroll
    for (int msub = 0; msub < 2; msub++){
      const u16* krh = kh  + bo + (size_t)(i0c + msub*16 + l15)*E_ + g*8;
      const u16* krl = klo + bo + (size_t)(i0c + msub*16 + l15)*E_ + g*8;
      bf16x8 kf_h0 = *(const bf16x8*)(krh);
      bf16x8 kf_h1 = *(const bf16x8*)(krh + 32);
      bf16x8 kf_l0 = *(const bf16x8*)(krl);
      bf16x8 kf_l1 = *(const bf16x8*)(krl + 32);
      f32x4 sacc = {0.f,0.f,0.f,0.f};
      sacc = MFMA16(kf_h0, qf_h0, sacc);
      sacc = MFMA16(kf_h1, qf_h1, sacc);
      sacc = MFMA16(kf_h0, qf_l0, sacc);
      sacc = MFMA16(kf_h1, qf_l1, sacc);
      sacc = MFMA16(kf_l0, qf_h0, sacc);
      sacc = MFMA16(kf_l1, qf_h1, sacc);
      // P rows i = i0c+msub*16+g*4+r, col j = j0+l15 (D: col=lane&15, row=(lane>>4)*4+r)
      f32x4 rlv = *(const f32x4*)&rlb[i0c + msub*16 + g*4];
      union { u16 u[4]; uint2 v2; } PH, PL;
      #pragma unroll
      for (int r = 0; r < 4; r++){
        float x = __expf(sacc[r]) * rlv[r];
        u16 hb = f2bf(x);
        float hf = bf2f(hb);
        PH.u[r] = hb;
        PL.u[r] = f2bf(x - hf);
      }
      int off = (msub*32 + g*8) ^ swz;
      *(uint2*)(PhB + l15*64 + off) = PH.v2;
      *(uint2*)(PlB + l15*64 + off) = PL.v2;
    }
    __syncthreads();   // single-wave: ~free, forces LDS ordering
    // PV B-frags: col j = l15, k i = g*8+t
    bf16x8 pf_h = *(const bf16x8*)(PhB + l15*64 + ((g*16) ^ swz));
    bf16x8 pf_l = *(const bf16x8*)(PlB + l15*64 + ((g*16) ^ swz));
    #pragma unroll
    for (int es = 0; es < 4; es++){
      int e = es*16 + l15;
      const u16* vrh = vh  + bo + (size_t)e*HW_ + i0c + g*8;
      const u16* vrl = vlo + bo + (size_t)e*HW_ + i0c + g*8;
      bf16x8 vf_h = *(const bf16x8*)(vrh);
      bf16x8 vf_l = *(const bf16x8*)(vrl);
      gacc[es] = MFMA16(vf_h, pf_h, gacc[es]);
      gacc[es] = MFMA16(vf_h, pf_l, gacc[es]);
      gacc[es] = MFMA16(vf_l, pf_h, gacc[es]);
    }
    __syncthreads();
  }
  // write partial: col j = j0+l15, row e = es*16 + g*4 + r
  float* gb = gsp + ((size_t)iz*B_ + b)*E_*HW_;
  #pragma unroll
  for (int es = 0; es < 4; es++){
    #pragma unroll
    for (int r = 0; r < 4; r++){
      int e = es*16 + g*4 + r;
      gb[(size_t)e*HW_ + j0 + l15] = gacc[es][r];
    }
  }
}

// ---- gsout[c,s] = sum_e watt[c,e]*(gs0+gs1)[e,s] + batt[c]  (staged in d_out) ----
__global__ __launch_bounds__(256) void k_gsout(const float* __restrict__ gsp,
    const float* __restrict__ watt, const float* __restrict__ batt,
    float* __restrict__ gsout){
  int b = blockIdx.x; int sc = blockIdx.y; int cc0 = blockIdx.z * 16;
  int s = sc*256 + threadIdx.x;
  __shared__ float lw[1024];
  for (int n = threadIdx.x; n < 1024; n += 256) lw[n] = watt[cc0*E_ + n];
  __syncthreads();
  const float* g0 = gsp + (size_t)b*E_*HW_ + s;
  const float* g1 = gsp + (size_t)(B_+b)*E_*HW_ + s;
  float acc[16];
  #pragma unroll
  for (int x = 0; x < 16; x++) acc[x] = 0.f;
  for (int e = 0; e < E_; e++){
    float gv = g0[(size_t)e*HW_] + g1[(size_t)e*HW_];
    #pragma unroll
    for (int x = 0; x < 16; x++) acc[x] += lw[x*64 + e] * gv;
  }
  float* ob = gsout + (size_t)b*SB_ + (size_t)cc0*HW_ + s;
  #pragma unroll
  for (int x = 0; x < 16; x++) ob[(size_t)x*HW_] = acc[x] + batt[cc0 + x];
}

// ---- final: gc GEMM (V @ att_c) fused with out = f*gc*(gsout+1), in-place on d_out ----
__global__ __launch_bounds__(256) void k_final(const float* __restrict__ f,
    const float* __restrict__ attc, const float* __restrict__ gsout,
    float* __restrict__ out){
  int b = blockIdx.x; int p0 = blockIdx.y * 64;
  int j = threadIdx.x;
  __shared__ float A[16384];
  const float* fb = f + (size_t)b*SB_ + (size_t)p0*C_;
  for (int n = j; n < 16384; n += 256) A[n] = fb[n];
  __syncthreads();
  const float* ab = attc + (size_t)b*C_*C_;
  float acc[64];
  #pragma unroll
  for (int p = 0; p < 64; p++) acc[p] = 0.f;
  for (int i = 0; i < C_; i++){
    float bv = ab[(size_t)i*C_ + j];
    #pragma unroll
    for (int p = 0; p < 64; p++) acc[p] += A[p*256 + i] * bv;
  }
  const float* gb = gsout + (size_t)b*SB_ + (size_t)p0*C_;
  float* ob = out + (size_t)b*SB_ + (size_t)p0*C_;
  #pragma unroll
  for (int p = 0; p < 64; p++){
    float fx = A[p*256 + j];
    float g  = gb[p*256 + j];
    ob[p*256 + j] = acc[p] * fx * (g + 1.f);
  }
}

extern "C" void kernel_launch(void* const* d_in, const int* in_sizes, int n_in,
                              void* d_out, int out_size, void* d_ws, size_t ws_size,
                              hipStream_t stream){
  const float* f    = (const float*)d_in[0];
  const float* wq1  = (const float*)d_in[1];
  const float* bq1  = (const float*)d_in[2];
  const float* wk1  = (const float*)d_in[3];
  const float* bk1  = (const float*)d_in[4];
  const float* wq2  = (const float*)d_in[5];
  const float* bq2  = (const float*)d_in[6];
  const float* wk2  = (const float*)d_in[7];
  const float* bk2  = (const float*)d_in[8];
  const float* wv2  = (const float*)d_in[9];
  const float* bv2  = (const float*)d_in[10];
  const float* watt = (const float*)d_in[11];
  const float* batt = (const float*)d_in[12];
  float* out = (float*)d_out;
  char* W = (char*)d_ws;

  // byte offsets (16B aligned); total ~25.9 MB
  float* gap   = (float*)(W + 0);          //    8192
  float* attc  = (float*)(W + 8192);       // 2097152
  float* lpart = (float*)(W + 2105344);    //  147456 (2 x B x HW)
  float* rl    = (float*)(W + 2252800);    //   73728
  float* gsp   = (float*)(W + 2326528);    // 9437184 (2 x B x E x HW)
  u16* qh  = (u16*)(W + 11763712);         // 2359296 each below
  u16* qlo = (u16*)(W + 14123008);
  u16* kh  = (u16*)(W + 16482304);
  u16* klo = (u16*)(W + 18841600);
  u16* vh  = (u16*)(W + 21200896);
  u16* vlo = (u16*)(W + 23560192);

  k_gap   <<<B_*C_,            256, 0, stream>>>(f, gap);
  k_attc  <<<B_*C_,            256, 0, stream>>>(gap, wq1, bq1, wk1, bk1, attc);
  k_proj3 <<<dim3(B_, 36, 3),  256, 0, stream>>>(f, wq2, bq2, wk2, bk2, wv2, bv2,
                                                 qh, qlo, kh, klo, vh, vlo);
  k_stats3<<<dim3(B_, 144, 2),  64, 0, stream>>>(qh, qlo, kh, klo, lpart);
  k_rl    <<<B_*HW_/256,       256, 0, stream>>>(lpart, rl);
  k_gs3   <<<dim3(B_, 144, 2),  64, 0, stream>>>(qh, qlo, kh, klo, vh, vlo, rl, gsp);
  k_gsout <<<dim3(B_, 9, 16),  256, 0, stream>>>(gsp, watt, batt, out);
  k_final <<<dim3(B_, 36),     256, 0, stream>>>(f, attc, out, out);
}

// Round 5
// 477.014 us; speedup vs baseline: 3.6600x; 1.0543x over previous
//
#include <hip/hip_runtime.h>

#define B_ 8
#define C_ 256
#define HW_ 2304
#define E_ 64
#define SB_ (C_*HW_)  // 589824 floats per batch

typedef unsigned short u16;
typedef __attribute__((ext_vector_type(8))) __bf16 bf16x8;
typedef __attribute__((ext_vector_type(4))) float f32x4;
#define MFMA16(a,b,c) __builtin_amdgcn_mfma_f32_16x16x32_bf16(a,b,c,0,0,0)

// fp32 -> bf16 RNE via integer ops
static __device__ inline u16 f2bf(float x){
  unsigned u = __builtin_bit_cast(unsigned, x);
  u += 0x7FFFu + ((u >> 16) & 1u);
  return (u16)(u >> 16);
}
static __device__ inline float bf2f(u16 h){
  unsigned u = ((unsigned)h) << 16;
  return __builtin_bit_cast(float, u);
}

// ---- GAP: mean over HW per (b,c) ----
__global__ __launch_bounds__(256) void k_gap(const float* __restrict__ f, float* __restrict__ gap){
  int bc = blockIdx.x;
  const float* row = f + (size_t)bc * HW_;
  float s = 0.f;
  for (int i = threadIdx.x; i < HW_; i += 256) s += row[i];
  #pragma unroll
  for (int off = 32; off; off >>= 1) s += __shfl_down(s, off);
  __shared__ float red[4];
  int lane = threadIdx.x & 63, wv = threadIdx.x >> 6;
  if (lane == 0) red[wv] = s;
  __syncthreads();
  if (threadIdx.x == 0) gap[bc] = (red[0]+red[1]+red[2]+red[3]) * (1.0f/HW_);
}

// ---- conv1d(k=3)+sigmoid, rank-1 scores, softmax over i -> bf16 hi/lo, TRANSPOSED [b][j][i] ----
__global__ __launch_bounds__(256) void k_attc2(const float* __restrict__ gap,
    const float* __restrict__ wq1, const float* __restrict__ bq1,
    const float* __restrict__ wk1, const float* __restrict__ bk1,
    u16* __restrict__ ath, u16* __restrict__ atl){
  int b = blockIdx.x >> 8;
  int j = blockIdx.x & 255;
  int i = threadIdx.x;
  const float* g = gap + b*C_;
  float gm1 = (i > 0)      ? g[i-1] : 0.f;
  float g0  = g[i];
  float gp1 = (i < C_-1)   ? g[i+1] : 0.f;
  float keyv = wk1[0]*gm1 + wk1[1]*g0 + wk1[2]*gp1 + bk1[0];
  keyv = 1.f/(1.f+__expf(-keyv));
  float qm1 = (j > 0)      ? g[j-1] : 0.f;
  float q0  = g[j];
  float qp1 = (j < C_-1)   ? g[j+1] : 0.f;
  float qv = wq1[0]*qm1 + wq1[1]*q0 + wq1[2]*qp1 + bq1[0];
  qv = 1.f/(1.f+__expf(-qv));
  float s = keyv * qv;
  __shared__ float red[256];
  red[i] = s; __syncthreads();
  for (int st = 128; st > 0; st >>= 1){ if (i < st) red[i] = fmaxf(red[i], red[i+st]); __syncthreads(); }
  float mx = red[0]; __syncthreads();
  float e = __expf(s - mx);
  red[i] = e; __syncthreads();
  for (int st = 128; st > 0; st >>= 1){ if (i < st) red[i] += red[i+st]; __syncthreads(); }
  float sum = red[0];
  float x = e / sum;
  u16 hb = f2bf(x);
  size_t o = ((size_t)b*C_ + j)*C_ + i;
  ath[o] = hb;
  atl[o] = f2bf(x - bf2f(hb));
}

// ---- q/k/v projections -> bf16 hi/lo; F tile in LDS; one matrix per block (z) ----
__global__ __launch_bounds__(256) void k_proj3(const float* __restrict__ f,
    const float* __restrict__ wq, const float* __restrict__ bq,
    const float* __restrict__ wk, const float* __restrict__ bk,
    const float* __restrict__ wv, const float* __restrict__ bv,
    u16* __restrict__ qh, u16* __restrict__ qlo,
    u16* __restrict__ kh, u16* __restrict__ klo,
    u16* __restrict__ vh, u16* __restrict__ vlo){
  int b = blockIdx.x; int s0 = blockIdx.y*64; int mz = blockIdx.z;
  int t = threadIdx.x;
  int sl = t & 63;
  int eg = t >> 6;
  __shared__ __align__(16) float F[C_*64];   // [c][sl], 64KB
  const float* fb = f + (size_t)b*SB_ + s0;
  #pragma unroll
  for (int it = 0; it < 16; it++){
    int n4 = t*4 + it*1024;
    int c = n4 >> 6, ss = n4 & 63;
    *(float4*)&F[n4] = *(const float4*)&fb[(size_t)c*HW_ + ss];
  }
  __syncthreads();
  int s = s0 + sl;
  int e0 = eg*16;
  const float* w  = (mz==0) ? wq : ((mz==1) ? wk : wv);
  const float* bi = (mz==0) ? bq : ((mz==1) ? bk : bv);
  float acc[16];
  #pragma unroll
  for (int e = 0; e < 16; e++) acc[e] = 0.f;
  for (int c4 = 0; c4 < 64; c4++){
    float fv[4];
    #pragma unroll
    for (int u = 0; u < 4; u++) fv[u] = F[(c4*4+u)*64 + sl];
    #pragma unroll
    for (int e = 0; e < 16; e++){
      float a = acc[e];
      #pragma unroll
      for (int u = 0; u < 4; u++) a += w[(e0+e)*C_ + c4*4 + u] * fv[u];
      acc[e] = a;
    }
  }
  if (mz < 2){
    u16* oh = (mz==0 ? qh : kh)  + ((size_t)b*HW_ + s)*E_ + e0;
    u16* ol = (mz==0 ? qlo: klo) + ((size_t)b*HW_ + s)*E_ + e0;
    union { u16 u[16]; uint4 v[2]; } H, L;
    #pragma unroll
    for (int tt = 0; tt < 16; tt++){
      float x = acc[tt] + bi[e0+tt];
      u16 hb = f2bf(x);
      float hf = bf2f(hb);
      L.u[tt] = f2bf(x - hf);
      H.u[tt] = hb;
    }
    *(uint4*)(oh)     = H.v[0];
    *(uint4*)(oh + 8) = H.v[1];
    *(uint4*)(ol)     = L.v[0];
    *(uint4*)(ol + 8) = L.v[1];
  } else {
    u16* ovh = vh  + (size_t)b*E_*HW_ + s;
    u16* ovl = vlo + (size_t)b*E_*HW_ + s;
    #pragma unroll
    for (int tt = 0; tt < 16; tt++){
      float x = acc[tt] + bi[e0+tt];
      u16 hb = f2bf(x);
      float hf = bf2f(hb);
      ovh[(size_t)(e0+tt)*HW_] = hb;
      ovl[(size_t)(e0+tt)*HW_] = f2bf(x - hf);
    }
  }
}

// ---- pass 1: partial row sums l_i over quarter j range. Single-wave blocks, 3 MFMA chains. ----
// grid (B, 144, 4): i-tile 16, j range = jz*576..+576.
__global__ __launch_bounds__(64) void k_stats4(
    const u16* __restrict__ qh, const u16* __restrict__ qlo,
    const u16* __restrict__ kh, const u16* __restrict__ klo,
    float* __restrict__ lpart){
  int b = blockIdx.x; int i0 = blockIdx.y*16; int jz = blockIdx.z;
  int lane = threadIdx.x; int l15 = lane & 15, g = lane >> 4;
  const size_t bo = (size_t)b*HW_*E_;
  const u16* krh = kh  + bo + (size_t)(i0 + l15)*E_ + g*8;
  const u16* krl = klo + bo + (size_t)(i0 + l15)*E_ + g*8;
  bf16x8 kf_h0 = *(const bf16x8*)(krh);
  bf16x8 kf_h1 = *(const bf16x8*)(krh + 32);
  bf16x8 kf_l0 = *(const bf16x8*)(krl);
  bf16x8 kf_l1 = *(const bf16x8*)(krl + 32);
  const u16* qhb = qh  + bo;
  const u16* qlb = qlo + bo;
  float lsum[4] = {0.f, 0.f, 0.f, 0.f};
  for (int jc = 0; jc < 18; jc++){
    int j = jz*576 + jc*32;
    #pragma unroll
    for (int nsub = 0; nsub < 2; nsub++){
      const u16* qrh = qhb + (size_t)(j + nsub*16 + l15)*E_ + g*8;
      const u16* qrl = qlb + (size_t)(j + nsub*16 + l15)*E_ + g*8;
      bf16x8 qf_h0 = *(const bf16x8*)(qrh);
      bf16x8 qf_h1 = *(const bf16x8*)(qrh + 32);
      bf16x8 qf_l0 = *(const bf16x8*)(qrl);
      bf16x8 qf_l1 = *(const bf16x8*)(qrl + 32);
      f32x4 c1 = {0.f,0.f,0.f,0.f}, c2 = {0.f,0.f,0.f,0.f}, c3 = {0.f,0.f,0.f,0.f};
      c1 = MFMA16(kf_h0, qf_h0, c1);
      c2 = MFMA16(kf_h0, qf_l0, c2);
      c3 = MFMA16(kf_l0, qf_h0, c3);
      c1 = MFMA16(kf_h1, qf_h1, c1);
      c2 = MFMA16(kf_h1, qf_l1, c2);
      c3 = MFMA16(kf_l1, qf_h1, c3);
      #pragma unroll
      for (int r = 0; r < 4; r++) lsum[r] += __expf(c1[r] + c2[r] + c3[r]);
    }
  }
  #pragma unroll
  for (int mk = 1; mk < 16; mk <<= 1){
    #pragma unroll
    for (int r = 0; r < 4; r++) lsum[r] += __shfl_xor(lsum[r], mk);
  }
  if (l15 == 0){
    float* lp = lpart + ((size_t)jz*B_ + b)*HW_ + i0 + g*4;
    #pragma unroll
    for (int r = 0; r < 4; r++) lp[r] = lsum[r];
  }
}

// ---- rl = 1/(l0+l1+l2+l3) ----
__global__ __launch_bounds__(256) void k_rl4(const float* __restrict__ lpart, float* __restrict__ rl){
  int i = blockIdx.x*256 + threadIdx.x;
  const int BH = B_*HW_;
  rl[i] = 1.0f / (lpart[i] + lpart[BH + i] + lpart[2*BH + i] + lpart[3*BH + i]);
}

// ---- pass 2: partial GS over quarter i range. Single-wave blocks, private LDS P bounce. ----
// grid (B, 144, 4): j-tile 16, i range = iz*576..+576 (18 chunks of 32).
__global__ __launch_bounds__(64) void k_gs4(
    const u16* __restrict__ qh, const u16* __restrict__ qlo,
    const u16* __restrict__ kh, const u16* __restrict__ klo,
    const u16* __restrict__ vh, const u16* __restrict__ vlo,
    const float* __restrict__ rl, float* __restrict__ gsp){
  int b = blockIdx.x; int j0 = blockIdx.y*16; int iz = blockIdx.z;
  int lane = threadIdx.x; int l15 = lane & 15, g = lane >> 4;
  __shared__ __align__(16) u16 Ph[2][16*32];
  __shared__ __align__(16) u16 Pl[2][16*32];
  const size_t bo = (size_t)b*HW_*E_;
  const u16* qrh = qh  + bo + (size_t)(j0 + l15)*E_ + g*8;
  const u16* qrl = qlo + bo + (size_t)(j0 + l15)*E_ + g*8;
  bf16x8 qf_h0 = *(const bf16x8*)(qrh);
  bf16x8 qf_h1 = *(const bf16x8*)(qrh + 32);
  bf16x8 qf_l0 = *(const bf16x8*)(qrl);
  bf16x8 qf_l1 = *(const bf16x8*)(qrl + 32);
  f32x4 gacc[4];
  #pragma unroll
  for (int es = 0; es < 4; es++) gacc[es] = (f32x4){0.f,0.f,0.f,0.f};
  const int swz = (l15 & 3) << 4;
  const float* rlb = rl + b*HW_;
  for (int ic = 0; ic < 18; ic++){
    int i0c = iz*576 + ic*32;
    int buf = ic & 1;
    char* PhB = (char*)&Ph[buf][0];
    char* PlB = (char*)&Pl[buf][0];
    #pragma unroll
    for (int msub = 0; msub < 2; msub++){
      const u16* krh = kh  + bo + (size_t)(i0c + msub*16 + l15)*E_ + g*8;
      const u16* krl = klo + bo + (size_t)(i0c + msub*16 + l15)*E_ + g*8;
      bf16x8 kf_h0 = *(const bf16x8*)(krh);
      bf16x8 kf_h1 = *(const bf16x8*)(krh + 32);
      bf16x8 kf_l0 = *(const bf16x8*)(krl);
      bf16x8 kf_l1 = *(const bf16x8*)(krl + 32);
      f32x4 c1 = {0.f,0.f,0.f,0.f}, c2 = {0.f,0.f,0.f,0.f}, c3 = {0.f,0.f,0.f,0.f};
      c1 = MFMA16(kf_h0, qf_h0, c1);
      c2 = MFMA16(kf_h0, qf_l0, c2);
      c3 = MFMA16(kf_l0, qf_h0, c3);
      c1 = MFMA16(kf_h1, qf_h1, c1);
      c2 = MFMA16(kf_h1, qf_l1, c2);
      c3 = MFMA16(kf_l1, qf_h1, c3);
      f32x4 rlv = *(const f32x4*)&rlb[i0c + msub*16 + g*4];
      union { u16 u[4]; uint2 v2; } PH, PL;
      #pragma unroll
      for (int r = 0; r < 4; r++){
        float x = __expf(c1[r] + c2[r] + c3[r]) * rlv[r];
        u16 hb = f2bf(x);
        float hf = bf2f(hb);
        PH.u[r] = hb;
        PL.u[r] = f2bf(x - hf);
      }
      int off = (msub*32 + g*8) ^ swz;
      *(uint2*)(PhB + l15*64 + off) = PH.v2;
      *(uint2*)(PlB + l15*64 + off) = PL.v2;
    }
    __syncthreads();
    bf16x8 pf_h = *(const bf16x8*)(PhB + l15*64 + ((g*16) ^ swz));
    bf16x8 pf_l = *(const bf16x8*)(PlB + l15*64 + ((g*16) ^ swz));
    #pragma unroll
    for (int es = 0; es < 4; es++){
      int e = es*16 + l15;
      const u16* vrh = vh  + bo + (size_t)e*HW_ + i0c + g*8;
      const u16* vrl = vlo + bo + (size_t)e*HW_ + i0c + g*8;
      bf16x8 vf_h = *(const bf16x8*)(vrh);
      bf16x8 vf_l = *(const bf16x8*)(vrl);
      gacc[es] = MFMA16(vf_h, pf_h, gacc[es]);
      gacc[es] = MFMA16(vf_h, pf_l, gacc[es]);
      gacc[es] = MFMA16(vf_l, pf_h, gacc[es]);
    }
    __syncthreads();
  }
  float* gb = gsp + ((size_t)iz*B_ + b)*E_*HW_;
  #pragma unroll
  for (int es = 0; es < 4; es++){
    #pragma unroll
    for (int r = 0; r < 4; r++){
      int e = es*16 + g*4 + r;
      gb[(size_t)e*HW_ + j0 + l15] = gacc[es][r];
    }
  }
}

// ---- gs = sum of 4 gsp partials (f32x4 elementwise) ----
__global__ __launch_bounds__(256) void k_gsum(const float* __restrict__ gsp, float* __restrict__ gs){
  const size_t N = (size_t)B_*E_*HW_;
  size_t n = ((size_t)blockIdx.x*256 + threadIdx.x)*4;
  f32x4 a = *(const f32x4*)(gsp + n);
  f32x4 b = *(const f32x4*)(gsp + N + n);
  f32x4 c = *(const f32x4*)(gsp + 2*N + n);
  f32x4 d = *(const f32x4*)(gsp + 3*N + n);
  *(f32x4*)(gs + n) = a + b + c + d;
}

// ---- gsout[c,s] = sum_e watt[c,e]*gs[e,s] + batt[c]; watt via uniform SGPR loads ----
__global__ __launch_bounds__(256) void k_gsout2(const float* __restrict__ gs,
    const float* __restrict__ watt, const float* __restrict__ batt,
    float* __restrict__ gsout){
  int b = blockIdx.x; int sc = blockIdx.y; int cc0 = blockIdx.z * 16;
  int s = sc*256 + threadIdx.x;
  const float* gb = gs + (size_t)b*E_*HW_ + s;
  float acc[16];
  #pragma unroll
  for (int x = 0; x < 16; x++) acc[x] = 0.f;
  for (int e = 0; e < E_; e++){
    float gv = gb[(size_t)e*HW_];
    #pragma unroll
    for (int x = 0; x < 16; x++) acc[x] += watt[(cc0+x)*E_ + e] * gv;   // uniform -> s_load
  }
  float* ob = gsout + (size_t)b*SB_ + (size_t)cc0*HW_ + s;
  #pragma unroll
  for (int x = 0; x < 16; x++) ob[(size_t)x*HW_] = acc[x] + batt[cc0 + x];
}

// ---- final: gc via MFMA (feature hi/lo x attc_t hi/lo), fused out = f*gc*(gsout+1) in-place ----
// grid (B, 144, 2): s-tile 16 rows, z = col half (8 col-tiles of 16). 1 wave.
__global__ __launch_bounds__(64) void k_final2(const float* __restrict__ f,
    const u16* __restrict__ ath, const u16* __restrict__ atl,
    float* __restrict__ inout){
  int b = blockIdx.x; int s0 = blockIdx.y*16; int z = blockIdx.z;
  int lane = threadIdx.x; int l15 = lane & 15, g = lane >> 4;
  const float* fb = f + (size_t)b*SB_;
  // A-frags on the fly: row s = s0+l15, elems c = ks*32+g*8+e  (f layout [c][hw], hw=flat s*256+j? no: A k-dim is c, row is s-position in flat [s][j]... row index here is the value-row s of V=f reshaped (hw,c): element V[s][c] = f_flat[s*256... careful: V raw-reshape (hw,c) means V[p][c] = f_flat[p*C_+c]. )
  // V[p][c] = f_flat[p*256 + c]; A-frag row p = s0+l15, k elems c contiguous -> 16B loads!
  bf16x8 Ah[8], Al[8];
  const float* arow = fb + (size_t)(s0 + l15)*C_;
  #pragma unroll
  for (int ks = 0; ks < 8; ks++){
    int cbase = ks*32 + g*8;
    float fe[8];
    #pragma unroll
    for (int e = 0; e < 8; e++) fe[e] = arow[cbase + e];
    union { u16 u[8]; bf16x8 v; } H, L;
    #pragma unroll
    for (int e = 0; e < 8; e++){
      u16 hb = f2bf(fe[e]);
      H.u[e] = hb;
      L.u[e] = f2bf(fe[e] - bf2f(hb));
    }
    Ah[ks] = H.v; Al[ks] = L.v;
  }
  const u16* ab_h = ath + (size_t)b*C_*C_;
  const u16* ab_l = atl + (size_t)b*C_*C_;
  f32x4 acc[8];
  #pragma unroll
  for (int q = 0; q < 8; q++) acc[q] = (f32x4){0.f,0.f,0.f,0.f};
  #pragma unroll
  for (int q = 0; q < 8; q++){
    int j = (z*8+q)*16 + l15;
    const u16* bh = ab_h + (size_t)j*C_ + g*8;
    const u16* bl = ab_l + (size_t)j*C_ + g*8;
    #pragma unroll
    for (int ks = 0; ks < 8; ks++){
      bf16x8 Bh = *(const bf16x8*)(bh + ks*32);
      bf16x8 Bl = *(const bf16x8*)(bl + ks*32);
      acc[q] = MFMA16(Ah[ks], Bh, acc[q]);
      acc[q] = MFMA16(Ah[ks], Bl, acc[q]);
      acc[q] = MFMA16(Al[ks], Bh, acc[q]);
    }
  }
  // out flat n = p*256 + j; gc[p][j] = acc; multiply f_flat[n]*(gsout[n]+1)
  float* ob = inout + (size_t)b*SB_;
  #pragma unroll
  for (int q = 0; q < 8; q++){
    #pragma unroll
    for (int r = 0; r < 4; r++){
      int p = s0 + g*4 + r;
      int j = (z*8+q)*16 + l15;
      size_t n = (size_t)p*C_ + j;
      float fx = fb[n];
      float gso = ob[n];
      ob[n] = acc[q][r] * fx * (gso + 1.f);
    }
  }
}

extern "C" void kernel_launch(void* const* d_in, const int* in_sizes, int n_in,
                              void* d_out, int out_size, void* d_ws, size_t ws_size,
                              hipStream_t stream){
  const float* f    = (const float*)d_in[0];
  const float* wq1  = (const float*)d_in[1];
  const float* bq1  = (const float*)d_in[2];
  const float* wk1  = (const float*)d_in[3];
  const float* bk1  = (const float*)d_in[4];
  const float* wq2  = (const float*)d_in[5];
  const float* bq2  = (const float*)d_in[6];
  const float* wk2  = (const float*)d_in[7];
  const float* bk2  = (const float*)d_in[8];
  const float* wv2  = (const float*)d_in[9];
  const float* bv2  = (const float*)d_in[10];
  const float* watt = (const float*)d_in[11];
  const float* batt = (const float*)d_in[12];
  float* out = (float*)d_out;
  char* W = (char*)d_ws;

  // byte offsets (16B aligned); total ~40.2 MB
  float* gap   = (float*)(W + 0);          //     8192
  u16*   ath   = (u16*)  (W + 8192);       //  1048576
  u16*   atl   = (u16*)  (W + 1056768);    //  1048576
  float* lpart = (float*)(W + 2105344);    //   294912 (4 x B x HW)
  float* rl    = (float*)(W + 2400256);    //    73728
  float* gsp   = (float*)(W + 2473984);    // 18874368 (4 x B x E x HW)
  float* gs    = (float*)(W + 21348352);   //  4718592
  u16* qh  = (u16*)(W + 26066944);         //  2359296 each below
  u16* qlo = (u16*)(W + 28426240);
  u16* kh  = (u16*)(W + 30785536);
  u16* klo = (u16*)(W + 33144832);
  u16* vh  = (u16*)(W + 35504128);
  u16* vlo = (u16*)(W + 37863424);

  k_gap   <<<B_*C_,             256, 0, stream>>>(f, gap);
  k_attc2 <<<B_*C_,             256, 0, stream>>>(gap, wq1, bq1, wk1, bk1, ath, atl);
  k_proj3 <<<dim3(B_, 36, 3),   256, 0, stream>>>(f, wq2, bq2, wk2, bk2, wv2, bv2,
                                                  qh, qlo, kh, klo, vh, vlo);
  k_stats4<<<dim3(B_, 144, 4),   64, 0, stream>>>(qh, qlo, kh, klo, lpart);
  k_rl4   <<<B_*HW_/256,        256, 0, stream>>>(lpart, rl);
  k_gs4   <<<dim3(B_, 144, 4),   64, 0, stream>>>(qh, qlo, kh, klo, vh, vlo, rl, gsp);
  k_gsum  <<<B_*E_*HW_/1024,    256, 0, stream>>>(gsp, gs);
  k_gsout2<<<dim3(B_, 9, 16),   256, 0, stream>>>(gs, watt, batt, out);
  k_final2<<<dim3(B_, 144, 2),   64, 0, stream>>>(f, ath, atl, out);
}

// Round 6
// 369.166 us; speedup vs baseline: 4.7292x; 1.2921x over previous
//
#include <hip/hip_runtime.h>

#define B_ 8
#define C_ 256
#define HW_ 2304
#define E_ 64
#define SB_ (C_*HW_)  // 589824 floats per batch

typedef unsigned short u16;
typedef __attribute__((ext_vector_type(8))) __bf16 bf16x8;
typedef __attribute__((ext_vector_type(4))) float f32x4;
#define MFMA16(a,b,c) __builtin_amdgcn_mfma_f32_16x16x32_bf16(a,b,c,0,0,0)

// LDS write->read ordering for a single-wave block WITHOUT draining vmcnt
// (__syncthreads would emit s_waitcnt vmcnt(0) and kill global-load pipelining)
#define LDS_FENCE() do { asm volatile("s_waitcnt lgkmcnt(0)" ::: "memory"); \
                         __builtin_amdgcn_sched_barrier(0); } while(0)

// fp32 -> bf16 RNE via integer ops
static __device__ inline u16 f2bf(float x){
  unsigned u = __builtin_bit_cast(unsigned, x);
  u += 0x7FFFu + ((u >> 16) & 1u);
  return (u16)(u >> 16);
}
static __device__ inline float bf2f(u16 h){
  unsigned u = ((unsigned)h) << 16;
  return __builtin_bit_cast(float, u);
}

// ---- GAP: mean over HW per (b,c) ----
__global__ __launch_bounds__(256) void k_gap(const float* __restrict__ f, float* __restrict__ gap){
  int bc = blockIdx.x;
  const float* row = f + (size_t)bc * HW_;
  float s = 0.f;
  for (int i = threadIdx.x; i < HW_; i += 256) s += row[i];
  #pragma unroll
  for (int off = 32; off; off >>= 1) s += __shfl_down(s, off);
  __shared__ float red[4];
  int lane = threadIdx.x & 63, wv = threadIdx.x >> 6;
  if (lane == 0) red[wv] = s;
  __syncthreads();
  if (threadIdx.x == 0) gap[bc] = (red[0]+red[1]+red[2]+red[3]) * (1.0f/HW_);
}

// ---- conv1d(k=3)+sigmoid, rank-1 scores, softmax over i -> bf16 hi/lo, TRANSPOSED [b][j][i] ----
__global__ __launch_bounds__(256) void k_attc2(const float* __restrict__ gap,
    const float* __restrict__ wq1, const float* __restrict__ bq1,
    const float* __restrict__ wk1, const float* __restrict__ bk1,
    u16* __restrict__ ath, u16* __restrict__ atl){
  int b = blockIdx.x >> 8;
  int j = blockIdx.x & 255;
  int i = threadIdx.x;
  const float* g = gap + b*C_;
  float gm1 = (i > 0)      ? g[i-1] : 0.f;
  float g0  = g[i];
  float gp1 = (i < C_-1)   ? g[i+1] : 0.f;
  float keyv = wk1[0]*gm1 + wk1[1]*g0 + wk1[2]*gp1 + bk1[0];
  keyv = 1.f/(1.f+__expf(-keyv));
  float qm1 = (j > 0)      ? g[j-1] : 0.f;
  float q0  = g[j];
  float qp1 = (j < C_-1)   ? g[j+1] : 0.f;
  float qv = wq1[0]*qm1 + wq1[1]*q0 + wq1[2]*qp1 + bq1[0];
  qv = 1.f/(1.f+__expf(-qv));
  float s = keyv * qv;
  __shared__ float red[256];
  red[i] = s; __syncthreads();
  for (int st = 128; st > 0; st >>= 1){ if (i < st) red[i] = fmaxf(red[i], red[i+st]); __syncthreads(); }
  float mx = red[0]; __syncthreads();
  float e = __expf(s - mx);
  red[i] = e; __syncthreads();
  for (int st = 128; st > 0; st >>= 1){ if (i < st) red[i] += red[i+st]; __syncthreads(); }
  float sum = red[0];
  float x = e / sum;
  u16 hb = f2bf(x);
  size_t o = ((size_t)b*C_ + j)*C_ + i;
  ath[o] = hb;
  atl[o] = f2bf(x - bf2f(hb));
}

// ---- q/k/v projections -> bf16 hi/lo; F tile in LDS; one matrix per block (z) ----
__global__ __launch_bounds__(256) void k_proj3(const float* __restrict__ f,
    const float* __restrict__ wq, const float* __restrict__ bq,
    const float* __restrict__ wk, const float* __restrict__ bk,
    const float* __restrict__ wv, const float* __restrict__ bv,
    u16* __restrict__ qh, u16* __restrict__ qlo,
    u16* __restrict__ kh, u16* __restrict__ klo,
    u16* __restrict__ vh, u16* __restrict__ vlo){
  int b = blockIdx.x; int s0 = blockIdx.y*64; int mz = blockIdx.z;
  int t = threadIdx.x;
  int sl = t & 63;
  int eg = t >> 6;
  __shared__ __align__(16) float F[C_*64];   // [c][sl], 64KB
  const float* fb = f + (size_t)b*SB_ + s0;
  #pragma unroll
  for (int it = 0; it < 16; it++){
    int n4 = t*4 + it*1024;
    int c = n4 >> 6, ss = n4 & 63;
    *(float4*)&F[n4] = *(const float4*)&fb[(size_t)c*HW_ + ss];
  }
  __syncthreads();
  int s = s0 + sl;
  int e0 = eg*16;
  const float* w  = (mz==0) ? wq : ((mz==1) ? wk : wv);
  const float* bi = (mz==0) ? bq : ((mz==1) ? bk : bv);
  float acc[16];
  #pragma unroll
  for (int e = 0; e < 16; e++) acc[e] = 0.f;
  for (int c4 = 0; c4 < 64; c4++){
    float fv[4];
    #pragma unroll
    for (int u = 0; u < 4; u++) fv[u] = F[(c4*4+u)*64 + sl];
    #pragma unroll
    for (int e = 0; e < 16; e++){
      float a = acc[e];
      #pragma unroll
      for (int u = 0; u < 4; u++) a += w[(e0+e)*C_ + c4*4 + u] * fv[u];
      acc[e] = a;
    }
  }
  if (mz < 2){
    u16* oh = (mz==0 ? qh : kh)  + ((size_t)b*HW_ + s)*E_ + e0;
    u16* ol = (mz==0 ? qlo: klo) + ((size_t)b*HW_ + s)*E_ + e0;
    union { u16 u[16]; uint4 v[2]; } H, L;
    #pragma unroll
    for (int tt = 0; tt < 16; tt++){
      float x = acc[tt] + bi[e0+tt];
      u16 hb = f2bf(x);
      float hf = bf2f(hb);
      L.u[tt] = f2bf(x - hf);
      H.u[tt] = hb;
    }
    *(uint4*)(oh)     = H.v[0];
    *(uint4*)(oh + 8) = H.v[1];
    *(uint4*)(ol)     = L.v[0];
    *(uint4*)(ol + 8) = L.v[1];
  } else {
    u16* ovh = vh  + (size_t)b*E_*HW_ + s;
    u16* ovl = vlo + (size_t)b*E_*HW_ + s;
    #pragma unroll
    for (int tt = 0; tt < 16; tt++){
      float x = acc[tt] + bi[e0+tt];
      u16 hb = f2bf(x);
      float hf = bf2f(hb);
      ovh[(size_t)(e0+tt)*HW_] = hb;
      ovl[(size_t)(e0+tt)*HW_] = f2bf(x - hf);
    }
  }
}

// ---- pass 1: partial row sums l_i, i-tile 32, j range 288. Single-wave, no barriers. ----
// grid (B, 72, 8)
__global__ __launch_bounds__(64) void k_stats5(
    const u16* __restrict__ qh, const u16* __restrict__ qlo,
    const u16* __restrict__ kh, const u16* __restrict__ klo,
    float* __restrict__ lpart){
  int b = blockIdx.x; int i0 = blockIdx.y*32; int jz = blockIdx.z;
  int lane = threadIdx.x; int l15 = lane & 15, g = lane >> 4;
  const size_t bo = (size_t)b*HW_*E_;
  bf16x8 kfh0[2], kfh1[2], kfl0[2], kfl1[2];
  #pragma unroll
  for (int isub = 0; isub < 2; isub++){
    const u16* krh = kh  + bo + (size_t)(i0 + isub*16 + l15)*E_ + g*8;
    const u16* krl = klo + bo + (size_t)(i0 + isub*16 + l15)*E_ + g*8;
    kfh0[isub] = *(const bf16x8*)(krh);
    kfh1[isub] = *(const bf16x8*)(krh + 32);
    kfl0[isub] = *(const bf16x8*)(krl);
    kfl1[isub] = *(const bf16x8*)(krl + 32);
  }
  const u16* qhb = qh  + bo;
  const u16* qlb = qlo + bo;
  float lsum[8];
  #pragma unroll
  for (int x = 0; x < 8; x++) lsum[x] = 0.f;
  for (int jc = 0; jc < 9; jc++){
    int j = jz*288 + jc*32;
    #pragma unroll
    for (int nsub = 0; nsub < 2; nsub++){
      const u16* qrh = qhb + (size_t)(j + nsub*16 + l15)*E_ + g*8;
      const u16* qrl = qlb + (size_t)(j + nsub*16 + l15)*E_ + g*8;
      bf16x8 qf_h0 = *(const bf16x8*)(qrh);
      bf16x8 qf_h1 = *(const bf16x8*)(qrh + 32);
      bf16x8 qf_l0 = *(const bf16x8*)(qrl);
      bf16x8 qf_l1 = *(const bf16x8*)(qrl + 32);
      #pragma unroll
      for (int isub = 0; isub < 2; isub++){
        f32x4 c1 = {0.f,0.f,0.f,0.f}, c2 = {0.f,0.f,0.f,0.f}, c3 = {0.f,0.f,0.f,0.f};
        c1 = MFMA16(kfh0[isub], qf_h0, c1);
        c2 = MFMA16(kfh0[isub], qf_l0, c2);
        c3 = MFMA16(kfl0[isub], qf_h0, c3);
        c1 = MFMA16(kfh1[isub], qf_h1, c1);
        c2 = MFMA16(kfh1[isub], qf_l1, c2);
        c3 = MFMA16(kfl1[isub], qf_h1, c3);
        #pragma unroll
        for (int r = 0; r < 4; r++) lsum[isub*4+r] += __expf(c1[r] + c2[r] + c3[r]);
      }
    }
  }
  #pragma unroll
  for (int mk = 1; mk < 16; mk <<= 1){
    #pragma unroll
    for (int x = 0; x < 8; x++) lsum[x] += __shfl_xor(lsum[x], mk);
  }
  if (l15 == 0){
    float* lp = lpart + ((size_t)jz*B_ + b)*HW_ + i0;
    #pragma unroll
    for (int isub = 0; isub < 2; isub++)
      #pragma unroll
      for (int r = 0; r < 4; r++) lp[isub*16 + g*4 + r] = lsum[isub*4+r];
  }
}

// ---- rl = 1/sum of 8 partials ----
__global__ __launch_bounds__(256) void k_rl8(const float* __restrict__ lpart, float* __restrict__ rl){
  int i = blockIdx.x*256 + threadIdx.x;
  const int BH = B_*HW_;
  float s = 0.f;
  #pragma unroll
  for (int p = 0; p < 8; p++) s += lpart[(size_t)p*BH + i];
  rl[i] = 1.0f / s;
}

// ---- pass 2: partial GS, j-tile 32, i range 288. Single-wave, LDS fence only. ----
// grid (B, 72, 8)
__global__ __launch_bounds__(64) void k_gs5(
    const u16* __restrict__ qh, const u16* __restrict__ qlo,
    const u16* __restrict__ kh, const u16* __restrict__ klo,
    const u16* __restrict__ vh, const u16* __restrict__ vlo,
    const float* __restrict__ rl, float* __restrict__ gsp){
  int b = blockIdx.x; int j0 = blockIdx.y*32; int iz = blockIdx.z;
  int lane = threadIdx.x; int l15 = lane & 15, g = lane >> 4;
  // P tiles: [buf][32 j rows][40 u16] rows padded to 80B -> 20-bank stride, ~2-way only
  __shared__ __align__(16) u16 Ph[2][32][40];
  __shared__ __align__(16) u16 Pl[2][32][40];
  const size_t bo = (size_t)b*HW_*E_;
  bf16x8 qfh0[2], qfh1[2], qfl0[2], qfl1[2];
  #pragma unroll
  for (int jt = 0; jt < 2; jt++){
    const u16* qrh = qh  + bo + (size_t)(j0 + jt*16 + l15)*E_ + g*8;
    const u16* qrl = qlo + bo + (size_t)(j0 + jt*16 + l15)*E_ + g*8;
    qfh0[jt] = *(const bf16x8*)(qrh);
    qfh1[jt] = *(const bf16x8*)(qrh + 32);
    qfl0[jt] = *(const bf16x8*)(qrl);
    qfl1[jt] = *(const bf16x8*)(qrl + 32);
  }
  f32x4 gacc[2][4];
  #pragma unroll
  for (int jt = 0; jt < 2; jt++)
    #pragma unroll
    for (int es = 0; es < 4; es++) gacc[jt][es] = (f32x4){0.f,0.f,0.f,0.f};
  const float* rlb = rl + b*HW_;
  for (int ic = 0; ic < 9; ic++){
    int i0c = iz*288 + ic*32;
    int buf = ic & 1;
    // ---- issue V loads early: they stay in flight under the whole S phase ----
    bf16x8 vfh[4], vfl[4];
    #pragma unroll
    for (int es = 0; es < 4; es++){
      int e = es*16 + l15;
      vfh[es] = *(const bf16x8*)(vh  + bo + (size_t)e*HW_ + i0c + g*8);
      vfl[es] = *(const bf16x8*)(vlo + bo + (size_t)e*HW_ + i0c + g*8);
    }
    // ---- S phase ----
    #pragma unroll
    for (int msub = 0; msub < 2; msub++){
      const u16* krh = kh  + bo + (size_t)(i0c + msub*16 + l15)*E_ + g*8;
      const u16* krl = klo + bo + (size_t)(i0c + msub*16 + l15)*E_ + g*8;
      bf16x8 kf_h0 = *(const bf16x8*)(krh);
      bf16x8 kf_h1 = *(const bf16x8*)(krh + 32);
      bf16x8 kf_l0 = *(const bf16x8*)(krl);
      bf16x8 kf_l1 = *(const bf16x8*)(krl + 32);
      f32x4 rlv = *(const f32x4*)&rlb[i0c + msub*16 + g*4];
      #pragma unroll
      for (int jt = 0; jt < 2; jt++){
        f32x4 c1 = {0.f,0.f,0.f,0.f}, c2 = {0.f,0.f,0.f,0.f}, c3 = {0.f,0.f,0.f,0.f};
        c1 = MFMA16(kf_h0, qfh0[jt], c1);
        c2 = MFMA16(kf_h0, qfl0[jt], c2);
        c3 = MFMA16(kf_l0, qfh0[jt], c3);
        c1 = MFMA16(kf_h1, qfh1[jt], c1);
        c2 = MFMA16(kf_h1, qfl1[jt], c2);
        c3 = MFMA16(kf_l1, qfh1[jt], c3);
        union { u16 u[4]; uint2 v2; } PH, PL;
        #pragma unroll
        for (int r = 0; r < 4; r++){
          float x = __expf(c1[r] + c2[r] + c3[r]) * rlv[r];
          u16 hb = f2bf(x);
          float hf = bf2f(hb);
          PH.u[r] = hb;
          PL.u[r] = f2bf(x - hf);
        }
        // row = jt*16+l15 (80B stride), i-offset = msub*32 + g*8 bytes
        char* PhB = (char*)&Ph[buf][0][0] + (jt*16 + l15)*80 + msub*32 + g*8;
        char* PlB = (char*)&Pl[buf][0][0] + (jt*16 + l15)*80 + msub*32 + g*8;
        *(uint2*)PhB = PH.v2;
        *(uint2*)PlB = PL.v2;
      }
    }
    LDS_FENCE();   // LDS write->read ordering only; vmcnt untouched
    // ---- PV phase ----
    #pragma unroll
    for (int jt = 0; jt < 2; jt++){
      bf16x8 pf_h = *(const bf16x8*)((char*)&Ph[buf][0][0] + (jt*16 + l15)*80 + g*16);
      bf16x8 pf_l = *(const bf16x8*)((char*)&Pl[buf][0][0] + (jt*16 + l15)*80 + g*16);
      #pragma unroll
      for (int es = 0; es < 4; es++){
        gacc[jt][es] = MFMA16(vfh[es], pf_h, gacc[jt][es]);
        gacc[jt][es] = MFMA16(vfh[es], pf_l, gacc[jt][es]);
        gacc[jt][es] = MFMA16(vfl[es], pf_h, gacc[jt][es]);
      }
    }
  }
  float* gb = gsp + ((size_t)iz*B_ + b)*E_*HW_;
  #pragma unroll
  for (int jt = 0; jt < 2; jt++)
    #pragma unroll
    for (int es = 0; es < 4; es++)
      #pragma unroll
      for (int r = 0; r < 4; r++){
        int e = es*16 + g*4 + r;
        gb[(size_t)e*HW_ + j0 + jt*16 + l15] = gacc[jt][es][r];
      }
}

// ---- gs = sum of 8 gsp partials ----
__global__ __launch_bounds__(256) void k_gsum8(const float* __restrict__ gsp, float* __restrict__ gs){
  const size_t N = (size_t)B_*E_*HW_;
  size_t n = ((size_t)blockIdx.x*256 + threadIdx.x)*4;
  f32x4 s = *(const f32x4*)(gsp + n);
  #pragma unroll
  for (int p = 1; p < 8; p++) s += *(const f32x4*)(gsp + (size_t)p*N + n);
  *(f32x4*)(gs + n) = s;
}

// ---- gsout[c,s] = sum_e watt[c,e]*gs[e,s] + batt[c]; watt via uniform SGPR loads ----
__global__ __launch_bounds__(256) void k_gsout2(const float* __restrict__ gs,
    const float* __restrict__ watt, const float* __restrict__ batt,
    float* __restrict__ gsout){
  int b = blockIdx.x; int sc = blockIdx.y; int cc0 = blockIdx.z * 16;
  int s = sc*256 + threadIdx.x;
  const float* gb = gs + (size_t)b*E_*HW_ + s;
  float acc[16];
  #pragma unroll
  for (int x = 0; x < 16; x++) acc[x] = 0.f;
  for (int e = 0; e < E_; e++){
    float gv = gb[(size_t)e*HW_];
    #pragma unroll
    for (int x = 0; x < 16; x++) acc[x] += watt[(cc0+x)*E_ + e] * gv;   // uniform -> s_load
  }
  float* ob = gsout + (size_t)b*SB_ + (size_t)cc0*HW_ + s;
  #pragma unroll
  for (int x = 0; x < 16; x++) ob[(size_t)x*HW_] = acc[x] + batt[cc0 + x];
}

// ---- final: gc via MFMA (feature hi/lo x attc_t hi/lo), fused out = f*gc*(gsout+1) in-place ----
__global__ __launch_bounds__(64) void k_final2(const float* __restrict__ f,
    const u16* __restrict__ ath, const u16* __restrict__ atl,
    float* __restrict__ inout){
  int b = blockIdx.x; int s0 = blockIdx.y*16; int z = blockIdx.z;
  int lane = threadIdx.x; int l15 = lane & 15, g = lane >> 4;
  const float* fb = f + (size_t)b*SB_;
  // V[p][c] = f_flat[p*256 + c]; A-frag row p = s0+l15, k elems c contiguous -> 16B loads
  bf16x8 Ah[8], Al[8];
  const float* arow = fb + (size_t)(s0 + l15)*C_;
  #pragma unroll
  for (int ks = 0; ks < 8; ks++){
    int cbase = ks*32 + g*8;
    float fe[8];
    #pragma unroll
    for (int e = 0; e < 8; e++) fe[e] = arow[cbase + e];
    union { u16 u[8]; bf16x8 v; } H, L;
    #pragma unroll
    for (int e = 0; e < 8; e++){
      u16 hb = f2bf(fe[e]);
      H.u[e] = hb;
      L.u[e] = f2bf(fe[e] - bf2f(hb));
    }
    Ah[ks] = H.v; Al[ks] = L.v;
  }
  const u16* ab_h = ath + (size_t)b*C_*C_;
  const u16* ab_l = atl + (size_t)b*C_*C_;
  f32x4 acc[8];
  #pragma unroll
  for (int q = 0; q < 8; q++) acc[q] = (f32x4){0.f,0.f,0.f,0.f};
  #pragma unroll
  for (int q = 0; q < 8; q++){
    int j = (z*8+q)*16 + l15;
    const u16* bh = ab_h + (size_t)j*C_ + g*8;
    const u16* bl = ab_l + (size_t)j*C_ + g*8;
    #pragma unroll
    for (int ks = 0; ks < 8; ks++){
      bf16x8 Bh = *(const bf16x8*)(bh + ks*32);
      bf16x8 Bl = *(const bf16x8*)(bl + ks*32);
      acc[q] = MFMA16(Ah[ks], Bh, acc[q]);
      acc[q] = MFMA16(Ah[ks], Bl, acc[q]);
      acc[q] = MFMA16(Al[ks], Bh, acc[q]);
    }
  }
  float* ob = inout + (size_t)b*SB_;
  #pragma unroll
  for (int q = 0; q < 8; q++){
    #pragma unroll
    for (int r = 0; r < 4; r++){
      int p = s0 + g*4 + r;
      int j = (z*8+q)*16 + l15;
      size_t n = (size_t)p*C_ + j;
      float fx = fb[n];
      float gso = ob[n];
      ob[n] = acc[q][r] * fx * (gso + 1.f);
    }
  }
}

extern "C" void kernel_launch(void* const* d_in, const int* in_sizes, int n_in,
                              void* d_out, int out_size, void* d_ws, size_t ws_size,
                              hipStream_t stream){
  const float* f    = (const float*)d_in[0];
  const float* wq1  = (const float*)d_in[1];
  const float* bq1  = (const float*)d_in[2];
  const float* wk1  = (const float*)d_in[3];
  const float* bk1  = (const float*)d_in[4];
  const float* wq2  = (const float*)d_in[5];
  const float* bq2  = (const float*)d_in[6];
  const float* wk2  = (const float*)d_in[7];
  const float* bk2  = (const float*)d_in[8];
  const float* wv2  = (const float*)d_in[9];
  const float* bv2  = (const float*)d_in[10];
  const float* watt = (const float*)d_in[11];
  const float* batt = (const float*)d_in[12];
  float* out = (float*)d_out;
  char* W = (char*)d_ws;

  // byte offsets (16B aligned); total = 59,392,000 B (~56.6 MiB)
  float* gap   = (float*)(W + 0);          //     8192
  u16*   ath   = (u16*)  (W + 8192);       //  1048576
  u16*   atl   = (u16*)  (W + 1056768);    //  1048576
  float* lpart = (float*)(W + 2105344);    //   589824 (8 x B x HW)
  float* rl    = (float*)(W + 2695168);    //    73728
  float* gsp   = (float*)(W + 2768896);    // 37748736 (8 x B x E x HW)
  float* gs    = (float*)(W + 40517632);   //  4718592
  u16* qh  = (u16*)(W + 45236224);         //  2359296 each below
  u16* qlo = (u16*)(W + 47595520);
  u16* kh  = (u16*)(W + 49954816);
  u16* klo = (u16*)(W + 52314112);
  u16* vh  = (u16*)(W + 54673408);
  u16* vlo = (u16*)(W + 57032704);

  k_gap   <<<B_*C_,             256, 0, stream>>>(f, gap);
  k_attc2 <<<B_*C_,             256, 0, stream>>>(gap, wq1, bq1, wk1, bk1, ath, atl);
  k_proj3 <<<dim3(B_, 36, 3),   256, 0, stream>>>(f, wq2, bq2, wk2, bk2, wv2, bv2,
                                                  qh, qlo, kh, klo, vh, vlo);
  k_stats5<<<dim3(B_, 72, 8),    64, 0, stream>>>(qh, qlo, kh, klo, lpart);
  k_rl8   <<<B_*HW_/256,        256, 0, stream>>>(lpart, rl);
  k_gs5   <<<dim3(B_, 72, 8),    64, 0, stream>>>(qh, qlo, kh, klo, vh, vlo, rl, gsp);
  k_gsum8 <<<B_*E_*HW_/1024,    256, 0, stream>>>(gsp, gs);
  k_gsout2<<<dim3(B_, 9, 16),   256, 0, stream>>>(gs, watt, batt, out);
  k_final2<<<dim3(B_, 144, 2),   64, 0, stream>>>(f, ath, atl, out);
}

// Round 7
// 281.647 us; speedup vs baseline: 6.1988x; 1.3107x over previous
//
#include <hip/hip_runtime.h>

#define B_ 8
#define C_ 256
#define HW_ 2304
#define E_ 64
#define SB_ (C_*HW_)  // 589824 floats per batch

typedef unsigned short u16;
typedef __attribute__((ext_vector_type(8))) __bf16 bf16x8;
typedef __attribute__((ext_vector_type(4))) float f32x4;
#define MFMA16(a,b,c) __builtin_amdgcn_mfma_f32_16x16x32_bf16(a,b,c,0,0,0)

// LDS write->read ordering for a single-wave block WITHOUT draining vmcnt
#define LDS_FENCE() do { asm volatile("s_waitcnt lgkmcnt(0)" ::: "memory"); \
                         __builtin_amdgcn_sched_barrier(0); } while(0)

// fp32 -> bf16 RNE via integer ops
static __device__ inline u16 f2bf(float x){
  unsigned u = __builtin_bit_cast(unsigned, x);
  u += 0x7FFFu + ((u >> 16) & 1u);
  return (u16)(u >> 16);
}
static __device__ inline float bf2f(u16 h){
  unsigned u = ((unsigned)h) << 16;
  return __builtin_bit_cast(float, u);
}

// ---- GAP: mean over HW per (b,c) ----
__global__ __launch_bounds__(256) void k_gap(const float* __restrict__ f, float* __restrict__ gap){
  int bc = blockIdx.x;
  const float* row = f + (size_t)bc * HW_;
  float s = 0.f;
  for (int i = threadIdx.x; i < HW_; i += 256) s += row[i];
  #pragma unroll
  for (int off = 32; off; off >>= 1) s += __shfl_down(s, off);
  __shared__ float red[4];
  int lane = threadIdx.x & 63, wv = threadIdx.x >> 6;
  if (lane == 0) red[wv] = s;
  __syncthreads();
  if (threadIdx.x == 0) gap[bc] = (red[0]+red[1]+red[2]+red[3]) * (1.0f/HW_);
}

// ---- conv1d(k=3)+sigmoid, rank-1 scores, softmax over i -> bf16 hi/lo, TRANSPOSED [b][j][i] ----
__global__ __launch_bounds__(256) void k_attc2(const float* __restrict__ gap,
    const float* __restrict__ wq1, const float* __restrict__ bq1,
    const float* __restrict__ wk1, const float* __restrict__ bk1,
    u16* __restrict__ ath, u16* __restrict__ atl){
  int b = blockIdx.x >> 8;
  int j = blockIdx.x & 255;
  int i = threadIdx.x;
  const float* g = gap + b*C_;
  float gm1 = (i > 0)      ? g[i-1] : 0.f;
  float g0  = g[i];
  float gp1 = (i < C_-1)   ? g[i+1] : 0.f;
  float keyv = wk1[0]*gm1 + wk1[1]*g0 + wk1[2]*gp1 + bk1[0];
  keyv = 1.f/(1.f+__expf(-keyv));
  float qm1 = (j > 0)      ? g[j-1] : 0.f;
  float q0  = g[j];
  float qp1 = (j < C_-1)   ? g[j+1] : 0.f;
  float qv = wq1[0]*qm1 + wq1[1]*q0 + wq1[2]*qp1 + bq1[0];
  qv = 1.f/(1.f+__expf(-qv));
  float s = keyv * qv;
  __shared__ float red[256];
  red[i] = s; __syncthreads();
  for (int st = 128; st > 0; st >>= 1){ if (i < st) red[i] = fmaxf(red[i], red[i+st]); __syncthreads(); }
  float mx = red[0]; __syncthreads();
  float e = __expf(s - mx);
  red[i] = e; __syncthreads();
  for (int st = 128; st > 0; st >>= 1){ if (i < st) red[i] += red[i+st]; __syncthreads(); }
  float sum = red[0];
  float x = e / sum;
  u16 hb = f2bf(x);
  size_t o = ((size_t)b*C_ + j)*C_ + i;
  ath[o] = hb;
  atl[o] = f2bf(x - bf2f(hb));
}

// ---- convert wq2/wk2/wv2 (E x C fp32) -> bf16 hi/lo [mz][e][c] ----
__global__ __launch_bounds__(256) void k_wcvt(const float* __restrict__ wq,
    const float* __restrict__ wk, const float* __restrict__ wv,
    u16* __restrict__ wbh, u16* __restrict__ wbl){
  int n = blockIdx.x*256 + threadIdx.x;     // 0..49151
  int mz = n >> 14; int idx = n & 16383;
  const float* w = (mz==0) ? wq : ((mz==1) ? wk : wv);
  float x = w[idx];
  u16 hb = f2bf(x);
  wbh[n] = hb;
  wbl[n] = f2bf(x - bf2f(hb));
}

// ---- q/k/v projections via MFMA. 1 wave per (b, p-tile 16, matrix). No LDS, no barriers. ----
// grid (B, 144, 3). A = W[e][c] (bf16 h/l), B-frag = f[c][p] gathered+split on the fly.
__global__ __launch_bounds__(64) void k_proj5(const float* __restrict__ f,
    const u16* __restrict__ wbh, const u16* __restrict__ wbl,
    const float* __restrict__ bq, const float* __restrict__ bk, const float* __restrict__ bv,
    u16* __restrict__ qh, u16* __restrict__ qlo,
    u16* __restrict__ kh, u16* __restrict__ klo,
    u16* __restrict__ vh, u16* __restrict__ vlo){
  int b = blockIdx.x; int p0 = blockIdx.y*16; int mz = blockIdx.z;
  int lane = threadIdx.x; int l15 = lane & 15, g = lane >> 4;
  const float* fb = f + (size_t)b*SB_ + p0 + l15;
  const u16* wh = wbh + mz*16384;
  const u16* wl = wbl + mz*16384;
  const float* bi = (mz==0) ? bq : ((mz==1) ? bk : bv);
  f32x4 c1[4], c2[4], c3[4];
  #pragma unroll
  for (int m = 0; m < 4; m++){
    c1[m] = (f32x4){0.f,0.f,0.f,0.f};
    c2[m] = (f32x4){0.f,0.f,0.f,0.f};
    c3[m] = (f32x4){0.f,0.f,0.f,0.f};
  }
  for (int ks = 0; ks < 8; ks++){
    int cb = ks*32 + g*8;
    float fe[8];
    #pragma unroll
    for (int u = 0; u < 8; u++) fe[u] = fb[(size_t)(cb + u)*HW_];
    union { u16 u[8]; bf16x8 v; } FH, FL;
    #pragma unroll
    for (int u = 0; u < 8; u++){
      u16 hb = f2bf(fe[u]);
      FH.u[u] = hb;
      FL.u[u] = f2bf(fe[u] - bf2f(hb));
    }
    #pragma unroll
    for (int m = 0; m < 4; m++){
      bf16x8 awh = *(const bf16x8*)(wh + (m*16 + l15)*C_ + cb);
      bf16x8 awl = *(const bf16x8*)(wl + (m*16 + l15)*C_ + cb);
      c1[m] = MFMA16(awh, FH.v, c1[m]);
      c2[m] = MFMA16(awh, FL.v, c2[m]);
      c3[m] = MFMA16(awl, FH.v, c3[m]);
    }
  }
  int p = p0 + l15;
  if (mz < 2){
    u16* oh = (mz==0 ? qh : kh)  + ((size_t)b*HW_ + p)*E_;
    u16* ol = (mz==0 ? qlo: klo) + ((size_t)b*HW_ + p)*E_;
    #pragma unroll
    for (int m = 0; m < 4; m++){
      union { u16 u[4]; uint2 v2; } H, L;
      #pragma unroll
      for (int r = 0; r < 4; r++){
        int e = m*16 + g*4 + r;
        float x = c1[m][r] + c2[m][r] + c3[m][r] + bi[e];
        u16 hb = f2bf(x);
        H.u[r] = hb;
        L.u[r] = f2bf(x - bf2f(hb));
      }
      *(uint2*)(oh + m*16 + g*4) = H.v2;
      *(uint2*)(ol + m*16 + g*4) = L.v2;
    }
  } else {
    u16* ovh = vh  + (size_t)b*E_*HW_ + p;
    u16* ovl = vlo + (size_t)b*E_*HW_ + p;
    #pragma unroll
    for (int m = 0; m < 4; m++){
      #pragma unroll
      for (int r = 0; r < 4; r++){
        int e = m*16 + g*4 + r;
        float x = c1[m][r] + c2[m][r] + c3[m][r] + bi[e];
        u16 hb = f2bf(x);
        ovh[(size_t)e*HW_] = hb;
        ovl[(size_t)e*HW_] = f2bf(x - bf2f(hb));
      }
    }
  }
}

// ---- pass 1: partial row sums l_i, i-tile 32, j range 288. Single-wave, no barriers. ----
// grid (B, 72, 8)
__global__ __launch_bounds__(64) void k_stats5(
    const u16* __restrict__ qh, const u16* __restrict__ qlo,
    const u16* __restrict__ kh, const u16* __restrict__ klo,
    float* __restrict__ lpart){
  int b = blockIdx.x; int i0 = blockIdx.y*32; int jz = blockIdx.z;
  int lane = threadIdx.x; int l15 = lane & 15, g = lane >> 4;
  const size_t bo = (size_t)b*HW_*E_;
  bf16x8 kfh0[2], kfh1[2], kfl0[2], kfl1[2];
  #pragma unroll
  for (int isub = 0; isub < 2; isub++){
    const u16* krh = kh  + bo + (size_t)(i0 + isub*16 + l15)*E_ + g*8;
    const u16* krl = klo + bo + (size_t)(i0 + isub*16 + l15)*E_ + g*8;
    kfh0[isub] = *(const bf16x8*)(krh);
    kfh1[isub] = *(const bf16x8*)(krh + 32);
    kfl0[isub] = *(const bf16x8*)(krl);
    kfl1[isub] = *(const bf16x8*)(krl + 32);
  }
  const u16* qhb = qh  + bo;
  const u16* qlb = qlo + bo;
  float lsum[8];
  #pragma unroll
  for (int x = 0; x < 8; x++) lsum[x] = 0.f;
  for (int jc = 0; jc < 9; jc++){
    int j = jz*288 + jc*32;
    #pragma unroll
    for (int nsub = 0; nsub < 2; nsub++){
      const u16* qrh = qhb + (size_t)(j + nsub*16 + l15)*E_ + g*8;
      const u16* qrl = qlb + (size_t)(j + nsub*16 + l15)*E_ + g*8;
      bf16x8 qf_h0 = *(const bf16x8*)(qrh);
      bf16x8 qf_h1 = *(const bf16x8*)(qrh + 32);
      bf16x8 qf_l0 = *(const bf16x8*)(qrl);
      bf16x8 qf_l1 = *(const bf16x8*)(qrl + 32);
      #pragma unroll
      for (int isub = 0; isub < 2; isub++){
        f32x4 c1 = {0.f,0.f,0.f,0.f}, c2 = {0.f,0.f,0.f,0.f}, c3 = {0.f,0.f,0.f,0.f};
        c1 = MFMA16(kfh0[isub], qf_h0, c1);
        c2 = MFMA16(kfh0[isub], qf_l0, c2);
        c3 = MFMA16(kfl0[isub], qf_h0, c3);
        c1 = MFMA16(kfh1[isub], qf_h1, c1);
        c2 = MFMA16(kfh1[isub], qf_l1, c2);
        c3 = MFMA16(kfl1[isub], qf_h1, c3);
        #pragma unroll
        for (int r = 0; r < 4; r++) lsum[isub*4+r] += __expf(c1[r] + c2[r] + c3[r]);
      }
    }
  }
  #pragma unroll
  for (int mk = 1; mk < 16; mk <<= 1){
    #pragma unroll
    for (int x = 0; x < 8; x++) lsum[x] += __shfl_xor(lsum[x], mk);
  }
  if (l15 == 0){
    float* lp = lpart + ((size_t)jz*B_ + b)*HW_ + i0;
    #pragma unroll
    for (int isub = 0; isub < 2; isub++)
      #pragma unroll
      for (int r = 0; r < 4; r++) lp[isub*16 + g*4 + r] = lsum[isub*4+r];
  }
}

// ---- rl = 1/sum of 8 partials ----
__global__ __launch_bounds__(256) void k_rl8(const float* __restrict__ lpart, float* __restrict__ rl){
  int i = blockIdx.x*256 + threadIdx.x;
  const int BH = B_*HW_;
  float s = 0.f;
  #pragma unroll
  for (int p = 0; p < 8; p++) s += lpart[(size_t)p*BH + i];
  rl[i] = 1.0f / s;
}

// ---- pass 2: partial GS, j-tile 32, i range 288. Single-wave, LDS fence only. ----
// grid (B, 72, 8)
__global__ __launch_bounds__(64) void k_gs5(
    const u16* __restrict__ qh, const u16* __restrict__ qlo,
    const u16* __restrict__ kh, const u16* __restrict__ klo,
    const u16* __restrict__ vh, const u16* __restrict__ vlo,
    const float* __restrict__ rl, float* __restrict__ gsp){
  int b = blockIdx.x; int j0 = blockIdx.y*32; int iz = blockIdx.z;
  int lane = threadIdx.x; int l15 = lane & 15, g = lane >> 4;
  __shared__ __align__(16) u16 Ph[2][32][40];
  __shared__ __align__(16) u16 Pl[2][32][40];
  const size_t bo = (size_t)b*HW_*E_;
  bf16x8 qfh0[2], qfh1[2], qfl0[2], qfl1[2];
  #pragma unroll
  for (int jt = 0; jt < 2; jt++){
    const u16* qrh = qh  + bo + (size_t)(j0 + jt*16 + l15)*E_ + g*8;
    const u16* qrl = qlo + bo + (size_t)(j0 + jt*16 + l15)*E_ + g*8;
    qfh0[jt] = *(const bf16x8*)(qrh);
    qfh1[jt] = *(const bf16x8*)(qrh + 32);
    qfl0[jt] = *(const bf16x8*)(qrl);
    qfl1[jt] = *(const bf16x8*)(qrl + 32);
  }
  f32x4 gacc[2][4];
  #pragma unroll
  for (int jt = 0; jt < 2; jt++)
    #pragma unroll
    for (int es = 0; es < 4; es++) gacc[jt][es] = (f32x4){0.f,0.f,0.f,0.f};
  const float* rlb = rl + b*HW_;
  for (int ic = 0; ic < 9; ic++){
    int i0c = iz*288 + ic*32;
    int buf = ic & 1;
    bf16x8 vfh[4], vfl[4];
    #pragma unroll
    for (int es = 0; es < 4; es++){
      int e = es*16 + l15;
      vfh[es] = *(const bf16x8*)(vh  + bo + (size_t)e*HW_ + i0c + g*8);
      vfl[es] = *(const bf16x8*)(vlo + bo + (size_t)e*HW_ + i0c + g*8);
    }
    #pragma unroll
    for (int msub = 0; msub < 2; msub++){
      const u16* krh = kh  + bo + (size_t)(i0c + msub*16 + l15)*E_ + g*8;
      const u16* krl = klo + bo + (size_t)(i0c + msub*16 + l15)*E_ + g*8;
      bf16x8 kf_h0 = *(const bf16x8*)(krh);
      bf16x8 kf_h1 = *(const bf16x8*)(krh + 32);
      bf16x8 kf_l0 = *(const bf16x8*)(krl);
      bf16x8 kf_l1 = *(const bf16x8*)(krl + 32);
      f32x4 rlv = *(const f32x4*)&rlb[i0c + msub*16 + g*4];
      #pragma unroll
      for (int jt = 0; jt < 2; jt++){
        f32x4 c1 = {0.f,0.f,0.f,0.f}, c2 = {0.f,0.f,0.f,0.f}, c3 = {0.f,0.f,0.f,0.f};
        c1 = MFMA16(kf_h0, qfh0[jt], c1);
        c2 = MFMA16(kf_h0, qfl0[jt], c2);
        c3 = MFMA16(kf_l0, qfh0[jt], c3);
        c1 = MFMA16(kf_h1, qfh1[jt], c1);
        c2 = MFMA16(kf_h1, qfl1[jt], c2);
        c3 = MFMA16(kf_l1, qfh1[jt], c3);
        union { u16 u[4]; uint2 v2; } PH, PL;
        #pragma unroll
        for (int r = 0; r < 4; r++){
          float x = __expf(c1[r] + c2[r] + c3[r]) * rlv[r];
          u16 hb = f2bf(x);
          float hf = bf2f(hb);
          PH.u[r] = hb;
          PL.u[r] = f2bf(x - hf);
        }
        char* PhB = (char*)&Ph[buf][0][0] + (jt*16 + l15)*80 + msub*32 + g*8;
        char* PlB = (char*)&Pl[buf][0][0] + (jt*16 + l15)*80 + msub*32 + g*8;
        *(uint2*)PhB = PH.v2;
        *(uint2*)PlB = PL.v2;
      }
    }
    LDS_FENCE();
    #pragma unroll
    for (int jt = 0; jt < 2; jt++){
      bf16x8 pf_h = *(const bf16x8*)((char*)&Ph[buf][0][0] + (jt*16 + l15)*80 + g*16);
      bf16x8 pf_l = *(const bf16x8*)((char*)&Pl[buf][0][0] + (jt*16 + l15)*80 + g*16);
      #pragma unroll
      for (int es = 0; es < 4; es++){
        gacc[jt][es] = MFMA16(vfh[es], pf_h, gacc[jt][es]);
        gacc[jt][es] = MFMA16(vfh[es], pf_l, gacc[jt][es]);
        gacc[jt][es] = MFMA16(vfl[es], pf_h, gacc[jt][es]);
      }
    }
  }
  float* gb = gsp + ((size_t)iz*B_ + b)*E_*HW_;
  #pragma unroll
  for (int jt = 0; jt < 2; jt++)
    #pragma unroll
    for (int es = 0; es < 4; es++)
      #pragma unroll
      for (int r = 0; r < 4; r++){
        int e = es*16 + g*4 + r;
        gb[(size_t)e*HW_ + j0 + jt*16 + l15] = gacc[jt][es][r];
      }
}

// ---- gs = sum of 8 gsp partials ----
__global__ __launch_bounds__(256) void k_gsum8(const float* __restrict__ gsp, float* __restrict__ gs){
  const size_t N = (size_t)B_*E_*HW_;
  size_t n = ((size_t)blockIdx.x*256 + threadIdx.x)*4;
  f32x4 s = *(const f32x4*)(gsp + n);
  #pragma unroll
  for (int p = 1; p < 8; p++) s += *(const f32x4*)(gsp + (size_t)p*N + n);
  *(f32x4*)(gs + n) = s;
}

// ---- gsout[c,s] = sum_e watt[c,e]*gs[e,s] + batt[c]; watt via uniform SGPR loads ----
__global__ __launch_bounds__(256) void k_gsout2(const float* __restrict__ gs,
    const float* __restrict__ watt, const float* __restrict__ batt,
    float* __restrict__ gsout){
  int b = blockIdx.x; int sc = blockIdx.y; int cc0 = blockIdx.z * 16;
  int s = sc*256 + threadIdx.x;
  const float* gb = gs + (size_t)b*E_*HW_ + s;
  float acc[16];
  #pragma unroll
  for (int x = 0; x < 16; x++) acc[x] = 0.f;
  for (int e = 0; e < E_; e++){
    float gv = gb[(size_t)e*HW_];
    #pragma unroll
    for (int x = 0; x < 16; x++) acc[x] += watt[(cc0+x)*E_ + e] * gv;   // uniform -> s_load
  }
  float* ob = gsout + (size_t)b*SB_ + (size_t)cc0*HW_ + s;
  #pragma unroll
  for (int x = 0; x < 16; x++) ob[(size_t)x*HW_] = acc[x] + batt[cc0 + x];
}

// ---- final: gc via MFMA (feature hi/lo x attc_t hi/lo), fused out = f*gc*(gsout+1) in-place ----
__global__ __launch_bounds__(64) void k_final2(const float* __restrict__ f,
    const u16* __restrict__ ath, const u16* __restrict__ atl,
    float* __restrict__ inout){
  int b = blockIdx.x; int s0 = blockIdx.y*16; int z = blockIdx.z;
  int lane = threadIdx.x; int l15 = lane & 15, g = lane >> 4;
  const float* fb = f + (size_t)b*SB_;
  bf16x8 Ah[8], Al[8];
  const float* arow = fb + (size_t)(s0 + l15)*C_;
  #pragma unroll
  for (int ks = 0; ks < 8; ks++){
    int cbase = ks*32 + g*8;
    float fe[8];
    #pragma unroll
    for (int e = 0; e < 8; e++) fe[e] = arow[cbase + e];
    union { u16 u[8]; bf16x8 v; } H, L;
    #pragma unroll
    for (int e = 0; e < 8; e++){
      u16 hb = f2bf(fe[e]);
      H.u[e] = hb;
      L.u[e] = f2bf(fe[e] - bf2f(hb));
    }
    Ah[ks] = H.v; Al[ks] = L.v;
  }
  const u16* ab_h = ath + (size_t)b*C_*C_;
  const u16* ab_l = atl + (size_t)b*C_*C_;
  f32x4 acc[8];
  #pragma unroll
  for (int q = 0; q < 8; q++) acc[q] = (f32x4){0.f,0.f,0.f,0.f};
  #pragma unroll
  for (int q = 0; q < 8; q++){
    int j = (z*8+q)*16 + l15;
    const u16* bh = ab_h + (size_t)j*C_ + g*8;
    const u16* bl = ab_l + (size_t)j*C_ + g*8;
    #pragma unroll
    for (int ks = 0; ks < 8; ks++){
      bf16x8 Bh = *(const bf16x8*)(bh + ks*32);
      bf16x8 Bl = *(const bf16x8*)(bl + ks*32);
      acc[q] = MFMA16(Ah[ks], Bh, acc[q]);
      acc[q] = MFMA16(Ah[ks], Bl, acc[q]);
      acc[q] = MFMA16(Al[ks], Bh, acc[q]);
    }
  }
  float* ob = inout + (size_t)b*SB_;
  #pragma unroll
  for (int q = 0; q < 8; q++){
    #pragma unroll
    for (int r = 0; r < 4; r++){
      int p = s0 + g*4 + r;
      int j = (z*8+q)*16 + l15;
      size_t n = (size_t)p*C_ + j;
      float fx = fb[n];
      float gso = ob[n];
      ob[n] = acc[q][r] * fx * (gso + 1.f);
    }
  }
}

extern "C" void kernel_launch(void* const* d_in, const int* in_sizes, int n_in,
                              void* d_out, int out_size, void* d_ws, size_t ws_size,
                              hipStream_t stream){
  const float* f    = (const float*)d_in[0];
  const float* wq1  = (const float*)d_in[1];
  const float* bq1  = (const float*)d_in[2];
  const float* wk1  = (const float*)d_in[3];
  const float* bk1  = (const float*)d_in[4];
  const float* wq2  = (const float*)d_in[5];
  const float* bq2  = (const float*)d_in[6];
  const float* wk2  = (const float*)d_in[7];
  const float* bk2  = (const float*)d_in[8];
  const float* wv2  = (const float*)d_in[9];
  const float* bv2  = (const float*)d_in[10];
  const float* watt = (const float*)d_in[11];
  const float* batt = (const float*)d_in[12];
  float* out = (float*)d_out;
  char* W = (char*)d_ws;

  // byte offsets (16B aligned)
  float* gap   = (float*)(W + 0);          //     8192
  u16*   ath   = (u16*)  (W + 8192);       //  1048576
  u16*   atl   = (u16*)  (W + 1056768);    //  1048576
  float* lpart = (float*)(W + 2105344);    //   589824 (8 x B x HW)
  float* rl    = (float*)(W + 2695168);    //    73728
  float* gsp   = (float*)(W + 2768896);    // 37748736 (8 x B x E x HW)
  float* gs    = (float*)(W + 40517632);   //  4718592
  u16* qh  = (u16*)(W + 45236224);         //  2359296 each below
  u16* qlo = (u16*)(W + 47595520);
  u16* kh  = (u16*)(W + 49954816);
  u16* klo = (u16*)(W + 52314112);
  u16* vh  = (u16*)(W + 54673408);
  u16* vlo = (u16*)(W + 57032704);
  u16* wbh = (u16*)(W + 59392000);         //    98304
  u16* wbl = (u16*)(W + 59490304);         //    98304  (total 59588608)

  k_gap   <<<B_*C_,             256, 0, stream>>>(f, gap);
  k_attc2 <<<B_*C_,             256, 0, stream>>>(gap, wq1, bq1, wk1, bk1, ath, atl);
  k_wcvt  <<<192,               256, 0, stream>>>(wq2, wk2, wv2, wbh, wbl);
  k_proj5 <<<dim3(B_, 144, 3),   64, 0, stream>>>(f, wbh, wbl, bq2, bk2, bv2,
                                                  qh, qlo, kh, klo, vh, vlo);
  k_stats5<<<dim3(B_, 72, 8),    64, 0, stream>>>(qh, qlo, kh, klo, lpart);
  k_rl8   <<<B_*HW_/256,        256, 0, stream>>>(lpart, rl);
  k_gs5   <<<dim3(B_, 72, 8),    64, 0, stream>>>(qh, qlo, kh, klo, vh, vlo, rl, gsp);
  k_gsum8 <<<B_*E_*HW_/1024,    256, 0, stream>>>(gsp, gs);
  k_gsout2<<<dim3(B_, 9, 16),   256, 0, stream>>>(gs, watt, batt, out);
  k_final2<<<dim3(B_, 144, 2),   64, 0, stream>>>(f, ath, atl, out);
}

// Round 8
// 179.527 us; speedup vs baseline: 9.7248x; 1.5688x over previous
//
#include <hip/hip_runtime.h>

#define B_ 8
#define C_ 256
#define HW_ 2304
#define E_ 64
#define SB_ (C_*HW_)  // 589824 floats per batch

typedef unsigned short u16;
typedef __attribute__((ext_vector_type(8))) __bf16 bf16x8;
typedef __attribute__((ext_vector_type(4))) float f32x4;
#define MFMA16(a,b,c) __builtin_amdgcn_mfma_f32_16x16x32_bf16(a,b,c,0,0,0)

// LDS write->read ordering for a single-wave block WITHOUT draining vmcnt
#define LDS_FENCE() do { asm volatile("s_waitcnt lgkmcnt(0)" ::: "memory"); \
                         __builtin_amdgcn_sched_barrier(0); } while(0)

// fp32 -> bf16 RNE via integer ops
static __device__ inline u16 f2bf(float x){
  unsigned u = __builtin_bit_cast(unsigned, x);
  u += 0x7FFFu + ((u >> 16) & 1u);
  return (u16)(u >> 16);
}
static __device__ inline float bf2f(u16 h){
  unsigned u = ((unsigned)h) << 16;
  return __builtin_bit_cast(float, u);
}

// Fragment-contiguous layouts (u16 units), lane = g*16 + l15:
//  Q/K:  ((b*144 + tile)*2 + kc)*512 + lane*8 + u   ; value (pos=tile*16+l15, e=kc*32+g*8+u)
//  V:    ((b*72 + ic)*4 + es)*512 + lane*8 + u      ; value (e=es*16+l15, i=ic*32+g*8+u)
//  attc: ((b*16 + jt)*8 + kc)*512 + lane*8 + u      ; value (j=jt*16+l15, i=kc*32+g*8+u)
//  W:    ((mz*4 + m)*8 + kc)*512 + lane*8 + u       ; value (e=m*16+l15, c=kc*32+g*8+u)

// ---- GAP: mean over HW per (b,c) ----
__global__ __launch_bounds__(256) void k_gap(const float* __restrict__ f, float* __restrict__ gap){
  int bc = blockIdx.x;
  const float* row = f + (size_t)bc * HW_;
  float s = 0.f;
  for (int i = threadIdx.x; i < HW_; i += 256) s += row[i];
  #pragma unroll
  for (int off = 32; off; off >>= 1) s += __shfl_down(s, off);
  __shared__ float red[4];
  int lane = threadIdx.x & 63, wv = threadIdx.x >> 6;
  if (lane == 0) red[wv] = s;
  __syncthreads();
  if (threadIdx.x == 0) gap[bc] = (red[0]+red[1]+red[2]+red[3]) * (1.0f/HW_);
}

// ---- conv1d(k=3)+sigmoid, rank-1 scores, softmax over i -> bf16 hi/lo in B-frag layout ----
__global__ __launch_bounds__(256) void k_attc2(const float* __restrict__ gap,
    const float* __restrict__ wq1, const float* __restrict__ bq1,
    const float* __restrict__ wk1, const float* __restrict__ bk1,
    u16* __restrict__ ath, u16* __restrict__ atl){
  int b = blockIdx.x >> 8;
  int j = blockIdx.x & 255;
  int i = threadIdx.x;
  const float* g = gap + b*C_;
  float gm1 = (i > 0)      ? g[i-1] : 0.f;
  float g0  = g[i];
  float gp1 = (i < C_-1)   ? g[i+1] : 0.f;
  float keyv = wk1[0]*gm1 + wk1[1]*g0 + wk1[2]*gp1 + bk1[0];
  keyv = 1.f/(1.f+__expf(-keyv));
  float qm1 = (j > 0)      ? g[j-1] : 0.f;
  float q0  = g[j];
  float qp1 = (j < C_-1)   ? g[j+1] : 0.f;
  float qv = wq1[0]*qm1 + wq1[1]*q0 + wq1[2]*qp1 + bq1[0];
  qv = 1.f/(1.f+__expf(-qv));
  float s = keyv * qv;
  __shared__ float red[256];
  red[i] = s; __syncthreads();
  for (int st = 128; st > 0; st >>= 1){ if (i < st) red[i] = fmaxf(red[i], red[i+st]); __syncthreads(); }
  float mx = red[0]; __syncthreads();
  float e = __expf(s - mx);
  red[i] = e; __syncthreads();
  for (int st = 128; st > 0; st >>= 1){ if (i < st) red[i] += red[i+st]; __syncthreads(); }
  float sum = red[0];
  float x = e / sum;
  u16 hb = f2bf(x);
  size_t o = (((size_t)b*16 + (j>>4))*8 + (i>>5))*512 + (((i&31)>>3)*16 + (j&15))*8 + (i&7);
  ath[o] = hb;
  atl[o] = f2bf(x - bf2f(hb));
}

// ---- convert wq2/wk2/wv2 (E x C fp32) -> bf16 hi/lo in A-frag layout ----
__global__ __launch_bounds__(256) void k_wcvt(const float* __restrict__ wq,
    const float* __restrict__ wk, const float* __restrict__ wv,
    u16* __restrict__ wbh, u16* __restrict__ wbl){
  int n = blockIdx.x*256 + threadIdx.x;     // 0..49151
  int mz = n >> 14; int idx = n & 16383;
  int e = idx >> 8, c = idx & 255;
  const float* w = (mz==0) ? wq : ((mz==1) ? wk : wv);
  float x = w[idx];
  u16 hb = f2bf(x);
  size_t widx = (((size_t)mz*4 + (e>>4))*8 + (c>>5))*512 + (((c&31)>>3)*16 + (e&15))*8 + (c&7);
  wbh[widx] = hb;
  wbl[widx] = f2bf(x - bf2f(hb));
}

// ---- q/k/v projections via MFMA. 1 wave per (b, p-tile 16, matrix). Frag-layout outputs. ----
// grid (B, 144, 3)
__global__ __launch_bounds__(64) void k_proj5(const float* __restrict__ f,
    const u16* __restrict__ wbh, const u16* __restrict__ wbl,
    const float* __restrict__ bq, const float* __restrict__ bk, const float* __restrict__ bv,
    u16* __restrict__ qh, u16* __restrict__ qlo,
    u16* __restrict__ kh, u16* __restrict__ klo,
    u16* __restrict__ vh, u16* __restrict__ vlo){
  int b = blockIdx.x; int p0 = blockIdx.y*16; int mz = blockIdx.z;
  int lane = threadIdx.x; int l15 = lane & 15, g = lane >> 4;
  const float* fb = f + (size_t)b*SB_ + p0 + l15;
  const u16* wh = wbh + (size_t)mz*16384;
  const u16* wl = wbl + (size_t)mz*16384;
  const float* bi = (mz==0) ? bq : ((mz==1) ? bk : bv);
  f32x4 c1[4], c2[4], c3[4];
  #pragma unroll
  for (int m = 0; m < 4; m++){
    c1[m] = (f32x4){0.f,0.f,0.f,0.f};
    c2[m] = (f32x4){0.f,0.f,0.f,0.f};
    c3[m] = (f32x4){0.f,0.f,0.f,0.f};
  }
  for (int ks = 0; ks < 8; ks++){
    int cb = ks*32 + g*8;
    float fe[8];
    #pragma unroll
    for (int u = 0; u < 8; u++) fe[u] = fb[(size_t)(cb + u)*HW_];
    union { u16 u[8]; bf16x8 v; } FH, FL;
    #pragma unroll
    for (int u = 0; u < 8; u++){
      u16 hb = f2bf(fe[u]);
      FH.u[u] = hb;
      FL.u[u] = f2bf(fe[u] - bf2f(hb));
    }
    #pragma unroll
    for (int m = 0; m < 4; m++){
      bf16x8 awh = *(const bf16x8*)(wh + (m*8 + ks)*512 + lane*8);
      bf16x8 awl = *(const bf16x8*)(wl + (m*8 + ks)*512 + lane*8);
      c1[m] = MFMA16(awh, FH.v, c1[m]);
      c2[m] = MFMA16(awh, FL.v, c2[m]);
      c3[m] = MFMA16(awl, FH.v, c3[m]);
    }
  }
  if (mz < 2){
    u16* ohb = (mz==0 ? qh : kh);
    u16* olb = (mz==0 ? qlo: klo);
    size_t tb = ((size_t)b*144 + blockIdx.y)*2;
    #pragma unroll
    for (int m = 0; m < 4; m++){
      union { u16 u[4]; uint2 v2; } H, L;
      #pragma unroll
      for (int r = 0; r < 4; r++){
        int e = m*16 + g*4 + r;
        float x = c1[m][r] + c2[m][r] + c3[m][r] + bi[e];
        u16 hb = f2bf(x);
        H.u[r] = hb;
        L.u[r] = f2bf(x - bf2f(hb));
      }
      int kc = m >> 1;
      int gc = (m & 1)*2 + (g >> 1);
      int ub = (g & 1)*4;
      size_t idx = (tb + kc)*512 + (gc*16 + l15)*8 + ub;
      *(uint2*)(ohb + idx) = H.v2;
      *(uint2*)(olb + idx) = L.v2;
    }
  } else {
    int ic = blockIdx.y >> 1;
    int half = blockIdx.y & 1;
    int gg = half*2 + (l15 >> 3);
    int uu = l15 & 7;
    size_t vb0 = ((size_t)b*72 + ic)*4;
    #pragma unroll
    for (int m = 0; m < 4; m++){
      #pragma unroll
      for (int r = 0; r < 4; r++){
        int e = m*16 + g*4 + r;
        float x = c1[m][r] + c2[m][r] + c3[m][r] + bi[e];
        u16 hb = f2bf(x);
        size_t idx = (vb0 + m)*512 + (gg*16 + (g*4 + r))*8 + uu;
        vh[idx] = hb;
        vlo[idx] = f2bf(x - bf2f(hb));
      }
    }
  }
}

// ---- pass 1: partial row sums l_i, i-tile 32, j range 288. Single-wave, no barriers. ----
// grid (B, 72, 8)
__global__ __launch_bounds__(64) void k_stats5(
    const u16* __restrict__ qh, const u16* __restrict__ qlo,
    const u16* __restrict__ kh, const u16* __restrict__ klo,
    float* __restrict__ lpart){
  int b = blockIdx.x; int jz = blockIdx.z;
  int lane = threadIdx.x; int l15 = lane & 15, g = lane >> 4;
  size_t kt = ((size_t)b*144 + blockIdx.y*2);
  bf16x8 kfh0[2], kfh1[2], kfl0[2], kfl1[2];
  #pragma unroll
  for (int isub = 0; isub < 2; isub++){
    kfh0[isub] = *(const bf16x8*)(kh  + ((kt+isub)*2 + 0)*512 + lane*8);
    kfh1[isub] = *(const bf16x8*)(kh  + ((kt+isub)*2 + 1)*512 + lane*8);
    kfl0[isub] = *(const bf16x8*)(klo + ((kt+isub)*2 + 0)*512 + lane*8);
    kfl1[isub] = *(const bf16x8*)(klo + ((kt+isub)*2 + 1)*512 + lane*8);
  }
  float lsum[8];
  #pragma unroll
  for (int x = 0; x < 8; x++) lsum[x] = 0.f;
  for (int jc = 0; jc < 9; jc++){
    #pragma unroll
    for (int nsub = 0; nsub < 2; nsub++){
      size_t qt = ((size_t)b*144 + jz*18 + jc*2 + nsub)*2;
      bf16x8 qf_h0 = *(const bf16x8*)(qh  + (qt+0)*512 + lane*8);
      bf16x8 qf_h1 = *(const bf16x8*)(qh  + (qt+1)*512 + lane*8);
      bf16x8 qf_l0 = *(const bf16x8*)(qlo + (qt+0)*512 + lane*8);
      bf16x8 qf_l1 = *(const bf16x8*)(qlo + (qt+1)*512 + lane*8);
      #pragma unroll
      for (int isub = 0; isub < 2; isub++){
        f32x4 c1 = {0.f,0.f,0.f,0.f}, c2 = {0.f,0.f,0.f,0.f}, c3 = {0.f,0.f,0.f,0.f};
        c1 = MFMA16(kfh0[isub], qf_h0, c1);
        c2 = MFMA16(kfh0[isub], qf_l0, c2);
        c3 = MFMA16(kfl0[isub], qf_h0, c3);
        c1 = MFMA16(kfh1[isub], qf_h1, c1);
        c2 = MFMA16(kfh1[isub], qf_l1, c2);
        c3 = MFMA16(kfl1[isub], qf_h1, c3);
        #pragma unroll
        for (int r = 0; r < 4; r++) lsum[isub*4+r] += __expf(c1[r] + c2[r] + c3[r]);
      }
    }
  }
  #pragma unroll
  for (int mk = 1; mk < 16; mk <<= 1){
    #pragma unroll
    for (int x = 0; x < 8; x++) lsum[x] += __shfl_xor(lsum[x], mk);
  }
  if (l15 == 0){
    float* lp = lpart + ((size_t)jz*B_ + b)*HW_ + blockIdx.y*32;
    #pragma unroll
    for (int isub = 0; isub < 2; isub++)
      #pragma unroll
      for (int r = 0; r < 4; r++) lp[isub*16 + g*4 + r] = lsum[isub*4+r];
  }
}

// ---- rl = 1/sum of 8 partials ----
__global__ __launch_bounds__(256) void k_rl8(const float* __restrict__ lpart, float* __restrict__ rl){
  int i = blockIdx.x*256 + threadIdx.x;
  const int BH = B_*HW_;
  float s = 0.f;
  #pragma unroll
  for (int p = 0; p < 8; p++) s += lpart[(size_t)p*BH + i];
  rl[i] = 1.0f / s;
}

// ---- pass 2: partial GS, j-tile 32, i range 288. Single-wave, LDS fence only. ----
// grid (B, 72, 8)
__global__ __launch_bounds__(64) void k_gs5(
    const u16* __restrict__ qh, const u16* __restrict__ qlo,
    const u16* __restrict__ kh, const u16* __restrict__ klo,
    const u16* __restrict__ vh, const u16* __restrict__ vlo,
    const float* __restrict__ rl, float* __restrict__ gsp){
  int b = blockIdx.x; int j0 = blockIdx.y*32; int iz = blockIdx.z;
  int lane = threadIdx.x; int l15 = lane & 15, g = lane >> 4;
  __shared__ __align__(16) u16 Ph[2][32][40];
  __shared__ __align__(16) u16 Pl[2][32][40];
  bf16x8 qfh0[2], qfh1[2], qfl0[2], qfl1[2];
  #pragma unroll
  for (int jt = 0; jt < 2; jt++){
    size_t qt = ((size_t)b*144 + blockIdx.y*2 + jt)*2;
    qfh0[jt] = *(const bf16x8*)(qh  + (qt+0)*512 + lane*8);
    qfh1[jt] = *(const bf16x8*)(qh  + (qt+1)*512 + lane*8);
    qfl0[jt] = *(const bf16x8*)(qlo + (qt+0)*512 + lane*8);
    qfl1[jt] = *(const bf16x8*)(qlo + (qt+1)*512 + lane*8);
  }
  f32x4 gacc[2][4];
  #pragma unroll
  for (int jt = 0; jt < 2; jt++)
    #pragma unroll
    for (int es = 0; es < 4; es++) gacc[jt][es] = (f32x4){0.f,0.f,0.f,0.f};
  const float* rlb = rl + b*HW_;
  for (int ic = 0; ic < 9; ic++){
    int i0c = iz*288 + ic*32;
    int buf = ic & 1;
    // V A-frags (dense 1KB loads), issued early
    bf16x8 vfh[4], vfl[4];
    size_t vc = (((size_t)b*72 + iz*9 + ic)*4);
    #pragma unroll
    for (int es = 0; es < 4; es++){
      vfh[es] = *(const bf16x8*)(vh  + (vc+es)*512 + lane*8);
      vfl[es] = *(const bf16x8*)(vlo + (vc+es)*512 + lane*8);
    }
    #pragma unroll
    for (int msub = 0; msub < 2; msub++){
      size_t it = ((size_t)b*144 + iz*18 + ic*2 + msub)*2;
      bf16x8 kf_h0 = *(const bf16x8*)(kh  + (it+0)*512 + lane*8);
      bf16x8 kf_h1 = *(const bf16x8*)(kh  + (it+1)*512 + lane*8);
      bf16x8 kf_l0 = *(const bf16x8*)(klo + (it+0)*512 + lane*8);
      bf16x8 kf_l1 = *(const bf16x8*)(klo + (it+1)*512 + lane*8);
      f32x4 rlv = *(const f32x4*)&rlb[i0c + msub*16 + g*4];
      #pragma unroll
      for (int jt = 0; jt < 2; jt++){
        f32x4 c1 = {0.f,0.f,0.f,0.f}, c2 = {0.f,0.f,0.f,0.f}, c3 = {0.f,0.f,0.f,0.f};
        c1 = MFMA16(kf_h0, qfh0[jt], c1);
        c2 = MFMA16(kf_h0, qfl0[jt], c2);
        c3 = MFMA16(kf_l0, qfh0[jt], c3);
        c1 = MFMA16(kf_h1, qfh1[jt], c1);
        c2 = MFMA16(kf_h1, qfl1[jt], c2);
        c3 = MFMA16(kf_l1, qfh1[jt], c3);
        union { u16 u[4]; uint2 v2; } PH, PL;
        #pragma unroll
        for (int r = 0; r < 4; r++){
          float x = __expf(c1[r] + c2[r] + c3[r]) * rlv[r];
          u16 hb = f2bf(x);
          float hf = bf2f(hb);
          PH.u[r] = hb;
          PL.u[r] = f2bf(x - hf);
        }
        char* PhB = (char*)&Ph[buf][0][0] + (jt*16 + l15)*80 + msub*32 + g*8;
        char* PlB = (char*)&Pl[buf][0][0] + (jt*16 + l15)*80 + msub*32 + g*8;
        *(uint2*)PhB = PH.v2;
        *(uint2*)PlB = PL.v2;
      }
    }
    LDS_FENCE();
    #pragma unroll
    for (int jt = 0; jt < 2; jt++){
      bf16x8 pf_h = *(const bf16x8*)((char*)&Ph[buf][0][0] + (jt*16 + l15)*80 + g*16);
      bf16x8 pf_l = *(const bf16x8*)((char*)&Pl[buf][0][0] + (jt*16 + l15)*80 + g*16);
      #pragma unroll
      for (int es = 0; es < 4; es++){
        gacc[jt][es] = MFMA16(vfh[es], pf_h, gacc[jt][es]);
        gacc[jt][es] = MFMA16(vfh[es], pf_l, gacc[jt][es]);
        gacc[jt][es] = MFMA16(vfl[es], pf_h, gacc[jt][es]);
      }
    }
  }
  float* gb = gsp + ((size_t)iz*B_ + b)*E_*HW_;
  #pragma unroll
  for (int jt = 0; jt < 2; jt++)
    #pragma unroll
    for (int es = 0; es < 4; es++)
      #pragma unroll
      for (int r = 0; r < 4; r++){
        int e = es*16 + g*4 + r;
        gb[(size_t)e*HW_ + j0 + jt*16 + l15] = gacc[jt][es][r];
      }
}

// ---- gs = sum of 8 gsp partials ----
__global__ __launch_bounds__(256) void k_gsum8(const float* __restrict__ gsp, float* __restrict__ gs){
  const size_t N = (size_t)B_*E_*HW_;
  size_t n = ((size_t)blockIdx.x*256 + threadIdx.x)*4;
  f32x4 s = *(const f32x4*)(gsp + n);
  #pragma unroll
  for (int p = 1; p < 8; p++) s += *(const f32x4*)(gsp + (size_t)p*N + n);
  *(f32x4*)(gs + n) = s;
}

// ---- gsout[c,s] = sum_e watt[c,e]*gs[e,s] + batt[c]; watt via uniform SGPR loads ----
__global__ __launch_bounds__(256) void k_gsout2(const float* __restrict__ gs,
    const float* __restrict__ watt, const float* __restrict__ batt,
    float* __restrict__ gsout){
  int b = blockIdx.x; int sc = blockIdx.y; int cc0 = blockIdx.z * 16;
  int s = sc*256 + threadIdx.x;
  const float* gb = gs + (size_t)b*E_*HW_ + s;
  float acc[16];
  #pragma unroll
  for (int x = 0; x < 16; x++) acc[x] = 0.f;
  for (int e = 0; e < E_; e++){
    float gv = gb[(size_t)e*HW_];
    #pragma unroll
    for (int x = 0; x < 16; x++) acc[x] += watt[(cc0+x)*E_ + e] * gv;   // uniform -> s_load
  }
  float* ob = gsout + (size_t)b*SB_ + (size_t)cc0*HW_ + s;
  #pragma unroll
  for (int x = 0; x < 16; x++) ob[(size_t)x*HW_] = acc[x] + batt[cc0 + x];
}

// ---- final: gc via MFMA (feature hi/lo x attc frag layout), fused out = f*gc*(gsout+1) ----
__global__ __launch_bounds__(64) void k_final2(const float* __restrict__ f,
    const u16* __restrict__ ath, const u16* __restrict__ atl,
    float* __restrict__ inout){
  int b = blockIdx.x; int s0 = blockIdx.y*16; int z = blockIdx.z;
  int lane = threadIdx.x; int l15 = lane & 15, g = lane >> 4;
  const float* fb = f + (size_t)b*SB_;
  bf16x8 Ah[8], Al[8];
  const float* arow = fb + (size_t)(s0 + l15)*C_;
  #pragma unroll
  for (int ks = 0; ks < 8; ks++){
    int cbase = ks*32 + g*8;
    float fe[8];
    #pragma unroll
    for (int e = 0; e < 8; e++) fe[e] = arow[cbase + e];
    union { u16 u[8]; bf16x8 v; } H, L;
    #pragma unroll
    for (int e = 0; e < 8; e++){
      u16 hb = f2bf(fe[e]);
      H.u[e] = hb;
      L.u[e] = f2bf(fe[e] - bf2f(hb));
    }
    Ah[ks] = H.v; Al[ks] = L.v;
  }
  const u16* abz_h = ath + (size_t)b*65536;
  const u16* abz_l = atl + (size_t)b*65536;
  f32x4 acc[8];
  #pragma unroll
  for (int q = 0; q < 8; q++) acc[q] = (f32x4){0.f,0.f,0.f,0.f};
  #pragma unroll
  for (int q = 0; q < 8; q++){
    int jt = z*8 + q;
    #pragma unroll
    for (int ks = 0; ks < 8; ks++){
      bf16x8 Bh = *(const bf16x8*)(abz_h + (jt*8 + ks)*512 + lane*8);
      bf16x8 Bl = *(const bf16x8*)(abz_l + (jt*8 + ks)*512 + lane*8);
      acc[q] = MFMA16(Ah[ks], Bh, acc[q]);
      acc[q] = MFMA16(Ah[ks], Bl, acc[q]);
      acc[q] = MFMA16(Al[ks], Bh, acc[q]);
    }
  }
  float* ob = inout + (size_t)b*SB_;
  #pragma unroll
  for (int q = 0; q < 8; q++){
    #pragma unroll
    for (int r = 0; r < 4; r++){
      int p = s0 + g*4 + r;
      int j = (z*8+q)*16 + l15;
      size_t n = (size_t)p*C_ + j;
      float fx = fb[n];
      float gso = ob[n];
      ob[n] = acc[q][r] * fx * (gso + 1.f);
    }
  }
}

extern "C" void kernel_launch(void* const* d_in, const int* in_sizes, int n_in,
                              void* d_out, int out_size, void* d_ws, size_t ws_size,
                              hipStream_t stream){
  const float* f    = (const float*)d_in[0];
  const float* wq1  = (const float*)d_in[1];
  const float* bq1  = (const float*)d_in[2];
  const float* wk1  = (const float*)d_in[3];
  const float* bk1  = (const float*)d_in[4];
  const float* wq2  = (const float*)d_in[5];
  const float* bq2  = (const float*)d_in[6];
  const float* wk2  = (const float*)d_in[7];
  const float* bk2  = (const float*)d_in[8];
  const float* wv2  = (const float*)d_in[9];
  const float* bv2  = (const float*)d_in[10];
  const float* watt = (const float*)d_in[11];
  const float* batt = (const float*)d_in[12];
  float* out = (float*)d_out;
  char* W = (char*)d_ws;

  // byte offsets (16B aligned); same sizes as round 7 (layouts changed, bytes identical)
  float* gap   = (float*)(W + 0);          //     8192
  u16*   ath   = (u16*)  (W + 8192);       //  1048576
  u16*   atl   = (u16*)  (W + 1056768);    //  1048576
  float* lpart = (float*)(W + 2105344);    //   589824 (8 x B x HW)
  float* rl    = (float*)(W + 2695168);    //    73728
  float* gsp   = (float*)(W + 2768896);    // 37748736 (8 x B x E x HW)
  float* gs    = (float*)(W + 40517632);   //  4718592
  u16* qh  = (u16*)(W + 45236224);         //  2359296 each below
  u16* qlo = (u16*)(W + 47595520);
  u16* kh  = (u16*)(W + 49954816);
  u16* klo = (u16*)(W + 52314112);
  u16* vh  = (u16*)(W + 54673408);
  u16* vlo = (u16*)(W + 57032704);
  u16* wbh = (u16*)(W + 59392000);         //    98304
  u16* wbl = (u16*)(W + 59490304);         //    98304  (total 59588608)

  k_gap   <<<B_*C_,             256, 0, stream>>>(f, gap);
  k_attc2 <<<B_*C_,             256, 0, stream>>>(gap, wq1, bq1, wk1, bk1, ath, atl);
  k_wcvt  <<<192,               256, 0, stream>>>(wq2, wk2, wv2, wbh, wbl);
  k_proj5 <<<dim3(B_, 144, 3),   64, 0, stream>>>(f, wbh, wbl, bq2, bk2, bv2,
                                                  qh, qlo, kh, klo, vh, vlo);
  k_stats5<<<dim3(B_, 72, 8),    64, 0, stream>>>(qh, qlo, kh, klo, lpart);
  k_rl8   <<<B_*HW_/256,        256, 0, stream>>>(lpart, rl);
  k_gs5   <<<dim3(B_, 72, 8),    64, 0, stream>>>(qh, qlo, kh, klo, vh, vlo, rl, gsp);
  k_gsum8 <<<B_*E_*HW_/1024,    256, 0, stream>>>(gsp, gs);
  k_gsout2<<<dim3(B_, 9, 16),   256, 0, stream>>>(gs, watt, batt, out);
  k_final2<<<dim3(B_, 144, 2),   64, 0, stream>>>(f, ath, atl, out);
}

// Round 9
// 162.449 us; speedup vs baseline: 10.7472x; 1.1051x over previous
//
#include <hip/hip_runtime.h>

#define B_ 8
#define C_ 256
#define HW_ 2304
#define E_ 64
#define SB_ (C_*HW_)  // 589824 floats per batch

typedef unsigned short u16;
typedef __attribute__((ext_vector_type(8))) __bf16 bf16x8;
typedef __attribute__((ext_vector_type(4))) float f32x4;
#define MFMA16(a,b,c) __builtin_amdgcn_mfma_f32_16x16x32_bf16(a,b,c,0,0,0)

// LDS write->read ordering for a single-wave block WITHOUT draining vmcnt
#define LDS_FENCE() do { asm volatile("s_waitcnt lgkmcnt(0)" ::: "memory"); \
                         __builtin_amdgcn_sched_barrier(0); } while(0)

// fp32 -> bf16 RNE via integer ops
static __device__ inline u16 f2bf(float x){
  unsigned u = __builtin_bit_cast(unsigned, x);
  u += 0x7FFFu + ((u >> 16) & 1u);
  return (u16)(u >> 16);
}
static __device__ inline float bf2f(u16 h){
  unsigned u = ((unsigned)h) << 16;
  return __builtin_bit_cast(float, u);
}

// Fragment-contiguous layouts (u16 units), lane = g*16 + l15:
//  Q/K:  (tile*2 + kc)*512 + lane*8 + u   ; tile = b*144 + pos/16, value (pos=tile*16+l15, e=kc*32+g*8+u)
//  V:    ((b*72 + ic)*4 + es)*512 + lane*8 + u      ; value (e=es*16+l15, i=ic*32+g*8+u)
//  attc: ((b*16 + jt)*8 + kc)*512 + lane*8 + u      ; value (j=jt*16+l15, i=kc*32+g*8+u)
//  W:    ((mz*4 + m)*8 + kc)*512 + lane*8 + u       ; value (e=m*16+l15, c=kc*32+g*8+u)

struct KFrag { bf16x8 h0, h1, l0, l1; };
static __device__ __forceinline__ KFrag ldfrag(const u16* __restrict__ ph,
                                               const u16* __restrict__ pl,
                                               size_t tile, int lane){
  KFrag q;
  q.h0 = *(const bf16x8*)(ph + (tile*2+0)*512 + (size_t)lane*8);
  q.h1 = *(const bf16x8*)(ph + (tile*2+1)*512 + (size_t)lane*8);
  q.l0 = *(const bf16x8*)(pl + (tile*2+0)*512 + (size_t)lane*8);
  q.l1 = *(const bf16x8*)(pl + (tile*2+1)*512 + (size_t)lane*8);
  return q;
}

// ---- GAP: mean over HW per (b,c) ----
__global__ __launch_bounds__(256) void k_gap(const float* __restrict__ f, float* __restrict__ gap){
  int bc = blockIdx.x;
  const float* row = f + (size_t)bc * HW_;
  float s = 0.f;
  for (int i = threadIdx.x; i < HW_; i += 256) s += row[i];
  #pragma unroll
  for (int off = 32; off; off >>= 1) s += __shfl_down(s, off);
  __shared__ float red[4];
  int lane = threadIdx.x & 63, wv = threadIdx.x >> 6;
  if (lane == 0) red[wv] = s;
  __syncthreads();
  if (threadIdx.x == 0) gap[bc] = (red[0]+red[1]+red[2]+red[3]) * (1.0f/HW_);
}

// ---- conv1d(k=3)+sigmoid, rank-1 scores, softmax over i -> bf16 hi/lo in B-frag layout ----
__global__ __launch_bounds__(256) void k_attc2(const float* __restrict__ gap,
    const float* __restrict__ wq1, const float* __restrict__ bq1,
    const float* __restrict__ wk1, const float* __restrict__ bk1,
    u16* __restrict__ ath, u16* __restrict__ atl){
  int b = blockIdx.x >> 8;
  int j = blockIdx.x & 255;
  int i = threadIdx.x;
  const float* g = gap + b*C_;
  float gm1 = (i > 0)      ? g[i-1] : 0.f;
  float g0  = g[i];
  float gp1 = (i < C_-1)   ? g[i+1] : 0.f;
  float keyv = wk1[0]*gm1 + wk1[1]*g0 + wk1[2]*gp1 + bk1[0];
  keyv = 1.f/(1.f+__expf(-keyv));
  float qm1 = (j > 0)      ? g[j-1] : 0.f;
  float q0  = g[j];
  float qp1 = (j < C_-1)   ? g[j+1] : 0.f;
  float qv = wq1[0]*qm1 + wq1[1]*q0 + wq1[2]*qp1 + bq1[0];
  qv = 1.f/(1.f+__expf(-qv));
  float s = keyv * qv;
  __shared__ float red[256];
  red[i] = s; __syncthreads();
  for (int st = 128; st > 0; st >>= 1){ if (i < st) red[i] = fmaxf(red[i], red[i+st]); __syncthreads(); }
  float mx = red[0]; __syncthreads();
  float e = __expf(s - mx);
  red[i] = e; __syncthreads();
  for (int st = 128; st > 0; st >>= 1){ if (i < st) red[i] += red[i+st]; __syncthreads(); }
  float sum = red[0];
  float x = e / sum;
  u16 hb = f2bf(x);
  size_t o = (((size_t)b*16 + (j>>4))*8 + (i>>5))*512 + (((i&31)>>3)*16 + (j&15))*8 + (i&7);
  ath[o] = hb;
  atl[o] = f2bf(x - bf2f(hb));
}

// ---- convert wq2/wk2/wv2 (E x C fp32) -> bf16 hi/lo in A-frag layout ----
__global__ __launch_bounds__(256) void k_wcvt(const float* __restrict__ wq,
    const float* __restrict__ wk, const float* __restrict__ wv,
    u16* __restrict__ wbh, u16* __restrict__ wbl){
  int n = blockIdx.x*256 + threadIdx.x;     // 0..49151
  int mz = n >> 14; int idx = n & 16383;
  int e = idx >> 8, c = idx & 255;
  const float* w = (mz==0) ? wq : ((mz==1) ? wk : wv);
  float x = w[idx];
  u16 hb = f2bf(x);
  size_t widx = (((size_t)mz*4 + (e>>4))*8 + (c>>5))*512 + (((c&31)>>3)*16 + (e&15))*8 + (c&7);
  wbh[widx] = hb;
  wbl[widx] = f2bf(x - bf2f(hb));
}

// ---- q/k/v projections via MFMA. 1 wave per (b, p-tile 16, matrix x e-half). ----
// grid (B, 144, 6): mz = z>>1, mh = z&1 (e-half)
__global__ __launch_bounds__(64) void k_proj6(const float* __restrict__ f,
    const u16* __restrict__ wbh, const u16* __restrict__ wbl,
    const float* __restrict__ bq, const float* __restrict__ bk, const float* __restrict__ bv,
    u16* __restrict__ qh, u16* __restrict__ qlo,
    u16* __restrict__ kh, u16* __restrict__ klo,
    u16* __restrict__ vh, u16* __restrict__ vlo){
  int b = blockIdx.x; int p0 = blockIdx.y*16;
  int mz = blockIdx.z >> 1, mh = blockIdx.z & 1;
  int lane = threadIdx.x; int l15 = lane & 15, g = lane >> 4;
  const float* fb = f + (size_t)b*SB_ + p0 + l15;
  const u16* wh = wbh + (size_t)mz*16384;
  const u16* wl = wbl + (size_t)mz*16384;
  const float* bi = (mz==0) ? bq : ((mz==1) ? bk : bv);
  f32x4 c1[2], c2[2], c3[2];
  #pragma unroll
  for (int m = 0; m < 2; m++){
    c1[m] = (f32x4){0.f,0.f,0.f,0.f};
    c2[m] = (f32x4){0.f,0.f,0.f,0.f};
    c3[m] = (f32x4){0.f,0.f,0.f,0.f};
  }
  #pragma unroll
  for (int ks = 0; ks < 8; ks++){
    int cb = ks*32 + g*8;
    float fe[8];
    #pragma unroll
    for (int u = 0; u < 8; u++) fe[u] = fb[(size_t)(cb + u)*HW_];
    union { u16 u[8]; bf16x8 v; } FH, FL;
    #pragma unroll
    for (int u = 0; u < 8; u++){
      u16 hb = f2bf(fe[u]);
      FH.u[u] = hb;
      FL.u[u] = f2bf(fe[u] - bf2f(hb));
    }
    #pragma unroll
    for (int ml = 0; ml < 2; ml++){
      int m = mh*2 + ml;
      bf16x8 awh = *(const bf16x8*)(wh + ((size_t)m*8 + ks)*512 + (size_t)lane*8);
      bf16x8 awl = *(const bf16x8*)(wl + ((size_t)m*8 + ks)*512 + (size_t)lane*8);
      c1[ml] = MFMA16(awh, FH.v, c1[ml]);
      c2[ml] = MFMA16(awh, FL.v, c2[ml]);
      c3[ml] = MFMA16(awl, FH.v, c3[ml]);
    }
  }
  if (mz < 2){
    u16* ohb = (mz==0 ? qh : kh);
    u16* olb = (mz==0 ? qlo: klo);
    size_t tb = ((size_t)b*144 + blockIdx.y)*2;
    #pragma unroll
    for (int ml = 0; ml < 2; ml++){
      int m = mh*2 + ml;
      union { u16 u[4]; uint2 v2; } H, L;
      #pragma unroll
      for (int r = 0; r < 4; r++){
        int e = m*16 + g*4 + r;
        float x = c1[ml][r] + c2[ml][r] + c3[ml][r] + bi[e];
        u16 hb = f2bf(x);
        H.u[r] = hb;
        L.u[r] = f2bf(x - bf2f(hb));
      }
      int kc = mh;                       // m>>1
      int gc = ml*2 + (g >> 1);          // (m&1)*2 + g/2
      int ub = (g & 1)*4;
      size_t idx = (tb + kc)*512 + (gc*16 + l15)*8 + ub;
      *(uint2*)(ohb + idx) = H.v2;
      *(uint2*)(olb + idx) = L.v2;
    }
  } else {
    int ic = blockIdx.y >> 1;
    int half = blockIdx.y & 1;
    int gg = half*2 + (l15 >> 3);
    int uu = l15 & 7;
    size_t vb0 = ((size_t)b*72 + ic)*4;
    #pragma unroll
    for (int ml = 0; ml < 2; ml++){
      int m = mh*2 + ml;
      #pragma unroll
      for (int r = 0; r < 4; r++){
        int e = m*16 + g*4 + r;
        float x = c1[ml][r] + c2[ml][r] + c3[ml][r] + bi[e];
        u16 hb = f2bf(x);
        size_t idx = (vb0 + m)*512 + (gg*16 + (g*4 + r))*8 + uu;
        vh[idx] = hb;
        vlo[idx] = f2bf(x - bf2f(hb));
      }
    }
  }
}

// ---- pass 1: partial row sums l_i, i-tile 32, j range 256 (16 tiles), fully unrolled. ----
// grid (B, 72, 9)
__global__ __launch_bounds__(64,2) void k_stats6(
    const u16* __restrict__ qh, const u16* __restrict__ qlo,
    const u16* __restrict__ kh, const u16* __restrict__ klo,
    float* __restrict__ lpart){
  int b = blockIdx.x; int it0 = blockIdx.y; int jz = blockIdx.z;
  int lane = threadIdx.x; int l15 = lane & 15, g = lane >> 4;
  const size_t b144 = (size_t)b*144;
  KFrag kf0 = ldfrag(kh, klo, b144 + it0*2,     lane);
  KFrag kf1 = ldfrag(kh, klo, b144 + it0*2 + 1, lane);
  float lsum[8];
  #pragma unroll
  for (int x = 0; x < 8; x++) lsum[x] = 0.f;
  size_t qb0 = b144 + jz*16;
  #pragma unroll
  for (int t = 0; t < 16; t++){
    KFrag q = ldfrag(qh, qlo, qb0 + t, lane);
    #pragma unroll
    for (int isub = 0; isub < 2; isub++){
      const KFrag& kf = isub ? kf1 : kf0;
      f32x4 c1 = {0.f,0.f,0.f,0.f}, c2 = {0.f,0.f,0.f,0.f}, c3 = {0.f,0.f,0.f,0.f};
      c1 = MFMA16(kf.h0, q.h0, c1);
      c2 = MFMA16(kf.h0, q.l0, c2);
      c3 = MFMA16(kf.l0, q.h0, c3);
      c1 = MFMA16(kf.h1, q.h1, c1);
      c2 = MFMA16(kf.h1, q.l1, c2);
      c3 = MFMA16(kf.l1, q.h1, c3);
      #pragma unroll
      for (int r = 0; r < 4; r++) lsum[isub*4+r] += __expf(c1[r] + c2[r] + c3[r]);
    }
  }
  #pragma unroll
  for (int mk = 1; mk < 16; mk <<= 1){
    #pragma unroll
    for (int x = 0; x < 8; x++) lsum[x] += __shfl_xor(lsum[x], mk);
  }
  if (l15 == 0){
    float* lp = lpart + ((size_t)jz*B_ + b)*HW_ + it0*32;
    #pragma unroll
    for (int isub = 0; isub < 2; isub++)
      #pragma unroll
      for (int r = 0; r < 4; r++) lp[isub*16 + g*4 + r] = lsum[isub*4+r];
  }
}

// ---- rl = 1/sum of 9 partials ----
__global__ __launch_bounds__(256) void k_rl9(const float* __restrict__ lpart, float* __restrict__ rl){
  int i = blockIdx.x*256 + threadIdx.x;
  const int BH = B_*HW_;
  float s = 0.f;
  #pragma unroll
  for (int p = 0; p < 9; p++) s += lpart[(size_t)p*BH + i];
  rl[i] = 1.0f / s;
}

// ---- pass 2: partial GS, j-tile 32, i range 384 (12 chunks). Depth-1 K-prefetch pipeline. ----
// grid (B, 72, 6)
__global__ __launch_bounds__(64,2) void k_gs6(
    const u16* __restrict__ qh, const u16* __restrict__ qlo,
    const u16* __restrict__ kh, const u16* __restrict__ klo,
    const u16* __restrict__ vh, const u16* __restrict__ vlo,
    const float* __restrict__ rl, float* __restrict__ gsp){
  int b = blockIdx.x; int jt0 = blockIdx.y; int iz = blockIdx.z;
  int j0 = jt0*32;
  int lane = threadIdx.x; int l15 = lane & 15, g = lane >> 4;
  // 10240B: P buffers during main loop; reused as f32 transpose tile in epilogue
  __shared__ __align__(16) char smem[10240];
  const size_t b144 = (size_t)b*144;
  KFrag qf0 = ldfrag(qh, qlo, b144 + jt0*2,     lane);
  KFrag qf1 = ldfrag(qh, qlo, b144 + jt0*2 + 1, lane);
  f32x4 gacc[2][4];
  #pragma unroll
  for (int jt = 0; jt < 2; jt++)
    #pragma unroll
    for (int es = 0; es < 4; es++) gacc[jt][es] = (f32x4){0.f,0.f,0.f,0.f};
  const float* rlb = rl + b*HW_;
  KFrag kcur0 = ldfrag(kh, klo, b144 + (size_t)iz*24,     lane);
  KFrag kcur1 = ldfrag(kh, klo, b144 + (size_t)iz*24 + 1, lane);
  #pragma unroll
  for (int ic = 0; ic < 12; ic++){
    int i0c = iz*384 + ic*32;
    // depth-1 prefetch of next chunk's K frags (issued BEFORE this chunk's fence)
    KFrag kn0 = kcur0, kn1 = kcur1;
    if (ic < 11){
      kn0 = ldfrag(kh, klo, b144 + (size_t)iz*24 + (ic+1)*2,     lane);
      kn1 = ldfrag(kh, klo, b144 + (size_t)iz*24 + (ic+1)*2 + 1, lane);
    }
    // V loads for current chunk (consumed after the fence, ~400cy of slack)
    bf16x8 vfh[4], vfl[4];
    size_t vc = ((size_t)b*72 + iz*12 + ic)*4;
    #pragma unroll
    for (int es = 0; es < 4; es++){
      vfh[es] = *(const bf16x8*)(vh  + (vc+es)*512 + (size_t)lane*8);
      vfl[es] = *(const bf16x8*)(vlo + (vc+es)*512 + (size_t)lane*8);
    }
    char* PhB = smem + (ic & 1)*2560;
    char* PlB = smem + 5120 + (ic & 1)*2560;
    #pragma unroll
    for (int msub = 0; msub < 2; msub++){
      const KFrag& kf = msub ? kcur1 : kcur0;
      f32x4 rlv = *(const f32x4*)&rlb[i0c + msub*16 + g*4];
      #pragma unroll
      for (int jt = 0; jt < 2; jt++){
        const KFrag& qf = jt ? qf1 : qf0;
        f32x4 c1 = {0.f,0.f,0.f,0.f}, c2 = {0.f,0.f,0.f,0.f}, c3 = {0.f,0.f,0.f,0.f};
        c1 = MFMA16(kf.h0, qf.h0, c1);
        c2 = MFMA16(kf.h0, qf.l0, c2);
        c3 = MFMA16(kf.l0, qf.h0, c3);
        c1 = MFMA16(kf.h1, qf.h1, c1);
        c2 = MFMA16(kf.h1, qf.l1, c2);
        c3 = MFMA16(kf.l1, qf.h1, c3);
        union { u16 u[4]; uint2 v2; } PH, PL;
        #pragma unroll
        for (int r = 0; r < 4; r++){
          float x = __expf(c1[r] + c2[r] + c3[r]) * rlv[r];
          u16 hb = f2bf(x);
          float hf = bf2f(hb);
          PH.u[r] = hb;
          PL.u[r] = f2bf(x - hf);
        }
        *(uint2*)(PhB + (jt*16 + l15)*80 + msub*32 + g*8) = PH.v2;
        *(uint2*)(PlB + (jt*16 + l15)*80 + msub*32 + g*8) = PL.v2;
      }
    }
    LDS_FENCE();
    #pragma unroll
    for (int jt = 0; jt < 2; jt++){
      bf16x8 pf_h = *(const bf16x8*)(PhB + (jt*16 + l15)*80 + g*16);
      bf16x8 pf_l = *(const bf16x8*)(PlB + (jt*16 + l15)*80 + g*16);
      #pragma unroll
      for (int es = 0; es < 4; es++){
        gacc[jt][es] = MFMA16(vfh[es], pf_h, gacc[jt][es]);
        gacc[jt][es] = MFMA16(vfh[es], pf_l, gacc[jt][es]);
        gacc[jt][es] = MFMA16(vfl[es], pf_h, gacc[jt][es]);
      }
    }
    kcur0 = kn0; kcur1 = kn1;
  }
  // ---- epilogue: transpose gacc through LDS -> full-line dwordx4 stores ----
  LDS_FENCE();                       // last PV ds_reads complete before overwrite
  float* GT = (float*)smem;          // 2048 floats = 8KB (within 10240)
  #pragma unroll
  for (int jt = 0; jt < 2; jt++)
    #pragma unroll
    for (int es = 0; es < 4; es++)
      #pragma unroll
      for (int r = 0; r < 4; r++)
        GT[(es*16 + g*4 + r)*32 + jt*16 + l15] = gacc[jt][es][r];
  LDS_FENCE();
  float* gb = gsp + ((size_t)iz*B_ + b)*E_*HW_;
  #pragma unroll
  for (int itx = 0; itx < 8; itx++){
    int n = (itx*64 + lane)*4;
    f32x4 vv = *(const f32x4*)&GT[n];
    int e = n >> 5, jj = n & 31;
    *(f32x4*)&gb[(size_t)e*HW_ + j0 + jj] = vv;
  }
}

// ---- gs = sum of 6 gsp partials ----
__global__ __launch_bounds__(256) void k_gsum6(const float* __restrict__ gsp, float* __restrict__ gs){
  const size_t N = (size_t)B_*E_*HW_;
  size_t n = ((size_t)blockIdx.x*256 + threadIdx.x)*4;
  f32x4 s = *(const f32x4*)(gsp + n);
  #pragma unroll
  for (int p = 1; p < 6; p++) s += *(const f32x4*)(gsp + (size_t)p*N + n);
  *(f32x4*)(gs + n) = s;
}

// ---- gsout[c,s] = sum_e watt[c,e]*gs[e,s] + batt[c]; watt via uniform SGPR loads ----
__global__ __launch_bounds__(256) void k_gsout2(const float* __restrict__ gs,
    const float* __restrict__ watt, const float* __restrict__ batt,
    float* __restrict__ gsout){
  int b = blockIdx.x; int sc = blockIdx.y; int cc0 = blockIdx.z * 16;
  int s = sc*256 + threadIdx.x;
  const float* gb = gs + (size_t)b*E_*HW_ + s;
  float acc[16];
  #pragma unroll
  for (int x = 0; x < 16; x++) acc[x] = 0.f;
  for (int e = 0; e < E_; e++){
    float gv = gb[(size_t)e*HW_];
    #pragma unroll
    for (int x = 0; x < 16; x++) acc[x] += watt[(cc0+x)*E_ + e] * gv;   // uniform -> s_load
  }
  float* ob = gsout + (size_t)b*SB_ + (size_t)cc0*HW_ + s;
  #pragma unroll
  for (int x = 0; x < 16; x++) ob[(size_t)x*HW_] = acc[x] + batt[cc0 + x];
}

// ---- final: gc via MFMA, fused out = f*gc*(gsout+1). grid (B, 144, 4): 4 j-tiles per wave ----
__global__ __launch_bounds__(64,2) void k_final3(const float* __restrict__ f,
    const u16* __restrict__ ath, const u16* __restrict__ atl,
    float* __restrict__ inout){
  int b = blockIdx.x; int s0 = blockIdx.y*16; int z = blockIdx.z;
  int lane = threadIdx.x; int l15 = lane & 15, g = lane >> 4;
  const float* fb = f + (size_t)b*SB_;
  bf16x8 Ah[8], Al[8];
  const float* arow = fb + (size_t)(s0 + l15)*C_;
  #pragma unroll
  for (int ks = 0; ks < 8; ks++){
    int cbase = ks*32 + g*8;
    float fe[8];
    #pragma unroll
    for (int e = 0; e < 8; e++) fe[e] = arow[cbase + e];
    union { u16 u[8]; bf16x8 v; } H, L;
    #pragma unroll
    for (int e = 0; e < 8; e++){
      u16 hb = f2bf(fe[e]);
      H.u[e] = hb;
      L.u[e] = f2bf(fe[e] - bf2f(hb));
    }
    Ah[ks] = H.v; Al[ks] = L.v;
  }
  const u16* abz_h = ath + (size_t)b*65536;
  const u16* abz_l = atl + (size_t)b*65536;
  f32x4 acc[4];
  #pragma unroll
  for (int q = 0; q < 4; q++) acc[q] = (f32x4){0.f,0.f,0.f,0.f};
  #pragma unroll
  for (int q = 0; q < 4; q++){
    int jt = z*4 + q;
    #pragma unroll
    for (int ks = 0; ks < 8; ks++){
      bf16x8 Bh = *(const bf16x8*)(abz_h + ((size_t)jt*8 + ks)*512 + (size_t)lane*8);
      bf16x8 Bl = *(const bf16x8*)(abz_l + ((size_t)jt*8 + ks)*512 + (size_t)lane*8);
      acc[q] = MFMA16(Ah[ks], Bh, acc[q]);
      acc[q] = MFMA16(Ah[ks], Bl, acc[q]);
      acc[q] = MFMA16(Al[ks], Bh, acc[q]);
    }
  }
  float* ob = inout + (size_t)b*SB_;
  #pragma unroll
  for (int q = 0; q < 4; q++){
    #pragma unroll
    for (int r = 0; r < 4; r++){
      int p = s0 + g*4 + r;
      int j = (z*4+q)*16 + l15;
      size_t n = (size_t)p*C_ + j;
      float fx = fb[n];
      float gso = ob[n];
      ob[n] = acc[q][r] * fx * (gso + 1.f);
    }
  }
}

extern "C" void kernel_launch(void* const* d_in, const int* in_sizes, int n_in,
                              void* d_out, int out_size, void* d_ws, size_t ws_size,
                              hipStream_t stream){
  const float* f    = (const float*)d_in[0];
  const float* wq1  = (const float*)d_in[1];
  const float* bq1  = (const float*)d_in[2];
  const float* wk1  = (const float*)d_in[3];
  const float* bk1  = (const float*)d_in[4];
  const float* wq2  = (const float*)d_in[5];
  const float* bq2  = (const float*)d_in[6];
  const float* wk2  = (const float*)d_in[7];
  const float* bk2  = (const float*)d_in[8];
  const float* wv2  = (const float*)d_in[9];
  const float* bv2  = (const float*)d_in[10];
  const float* watt = (const float*)d_in[11];
  const float* batt = (const float*)d_in[12];
  float* out = (float*)d_out;
  char* W = (char*)d_ws;

  // byte offsets (16B aligned); total = 52,215,808 B
  float* gap   = (float*)(W + 0);          //     8192
  u16*   ath   = (u16*)  (W + 8192);       //  1048576
  u16*   atl   = (u16*)  (W + 1056768);    //  1048576
  float* lpart = (float*)(W + 2105344);    //  2654208 (9 x B x HW)
  float* rl    = (float*)(W + 4759552);    //    73728
  float* gsp   = (float*)(W + 4833280);    // 28311552 (6 x B x E x HW)
  float* gs    = (float*)(W + 33144832);   //  4718592
  u16* qh  = (u16*)(W + 37863424);         //  2359296 each below
  u16* qlo = (u16*)(W + 40222720);
  u16* kh  = (u16*)(W + 42582016);
  u16* klo = (u16*)(W + 44941312);
  u16* vh  = (u16*)(W + 47300608);
  u16* vlo = (u16*)(W + 49659904);
  u16* wbh = (u16*)(W + 52019200);         //    98304
  u16* wbl = (u16*)(W + 52117504);         //    98304

  k_gap   <<<B_*C_,             256, 0, stream>>>(f, gap);
  k_attc2 <<<B_*C_,             256, 0, stream>>>(gap, wq1, bq1, wk1, bk1, ath, atl);
  k_wcvt  <<<192,               256, 0, stream>>>(wq2, wk2, wv2, wbh, wbl);
  k_proj6 <<<dim3(B_, 144, 6),   64, 0, stream>>>(f, wbh, wbl, bq2, bk2, bv2,
                                                  qh, qlo, kh, klo, vh, vlo);
  k_stats6<<<dim3(B_, 72, 9),    64, 0, stream>>>(qh, qlo, kh, klo, lpart);
  k_rl9   <<<B_*HW_/256,        256, 0, stream>>>(lpart, rl);
  k_gs6   <<<dim3(B_, 72, 6),    64, 0, stream>>>(qh, qlo, kh, klo, vh, vlo, rl, gsp);
  k_gsum6 <<<B_*E_*HW_/1024,    256, 0, stream>>>(gsp, gs);
  k_gsout2<<<dim3(B_, 9, 16),   256, 0, stream>>>(gs, watt, batt, out);
  k_final3<<<dim3(B_, 144, 4),   64, 0, stream>>>(f, ath, atl, out);
}